// Round 4
// baseline (1728.486 us; speedup 1.0000x reference)
//
#include <hip/hip_runtime.h>

#define N_NODES 50000
#define NPAD 50048            // padded row count (multiple of 64)
#define FEAT 256
#define HID 64
#define NEDGE 800000
#define SCAN_CHUNK 2048
#define NB_SCAN 25  // ceil(50000/2048)

// ---------------- tiled GEMM: embed  r0 = relu(x @ We) ----------------
// BM=64 rows/block, BN=64 (full), BK=16. 256 threads = 4 waves.
// lane = output col; wave w owns rows w*16..w*16+15 (acc[16]).
__global__ __launch_bounds__(256, 4) void embed_kernel(const float* __restrict__ x,
        const float* __restrict__ we, float* __restrict__ r0) {
    __shared__ float lds_a[64 * 16];
    __shared__ float lds_w[16 * 64];
    const int t    = threadIdx.x;
    const int lane = t & 63;
    const int wv   = t >> 6;
    const int row0 = blockIdx.x * 64;
    const int srow = t >> 2;          // 0..63  (act stage row)
    const int scol = (t & 3) * 4;     // 0,4,8,12
    const int wrow = t >> 4;          // 0..15  (weight stage k-row)
    const int wcol = (t & 15) * 4;

    // clamped source row for x (x is exactly N_NODES rows)
    const int asrc = (row0 + srow < N_NODES) ? (row0 + srow) : (N_NODES - 1);

    float acc[16];
#pragma unroll
    for (int r = 0; r < 16; ++r) acc[r] = 0.f;

    float4 pa = *(const float4*)(x + (size_t)asrc * FEAT + scol);
    float4 pw = *(const float4*)(we + (size_t)wrow * 64 + wcol);
    *(float4*)&lds_a[srow * 16 + scol] = pa;
    *(float4*)&lds_w[wrow * 64 + wcol] = pw;
    __syncthreads();

    const int NSTEP = FEAT / 16;  // 16
    for (int step = 0; step < NSTEP; ++step) {
        if (step + 1 < NSTEP) {   // prefetch next k-tile into regs
            int kt = (step + 1) * 16;
            pa = *(const float4*)(x + (size_t)asrc * FEAT + kt + scol);
            pw = *(const float4*)(we + (size_t)(kt + wrow) * 64 + wcol);
        }
#pragma unroll
        for (int kk4 = 0; kk4 < 4; ++kk4) {
            float w0 = lds_w[(kk4 * 4 + 0) * 64 + lane];
            float w1 = lds_w[(kk4 * 4 + 1) * 64 + lane];
            float w2 = lds_w[(kk4 * 4 + 2) * 64 + lane];
            float w3 = lds_w[(kk4 * 4 + 3) * 64 + lane];
#pragma unroll
            for (int rr = 0; rr < 16; ++rr) {
                float4 a4 = *(const float4*)&lds_a[(wv * 16 + rr) * 16 + kk4 * 4];
                acc[rr] += a4.x * w0 + a4.y * w1 + a4.z * w2 + a4.w * w3;
            }
        }
        __syncthreads();
        if (step + 1 < NSTEP) {
            *(float4*)&lds_a[srow * 16 + scol] = pa;
            *(float4*)&lds_w[wrow * 64 + wcol] = pw;
        }
        __syncthreads();
    }

#pragma unroll
    for (int rr = 0; rr < 16; ++rr) {
        int rv = row0 + wv * 16 + rr;
        if (rv < N_NODES)
            r0[(size_t)rv * HID + lane] = fmaxf(acc[rr], 0.f);
    }
}

// ---------------- CSR build ----------------
__global__ __launch_bounds__(256) void hist_kernel(const int* __restrict__ rows,
        int* __restrict__ cnt) {
    int e = blockIdx.x * 256 + threadIdx.x;
    if (e < NEDGE) atomicAdd(&cnt[rows[e]], 1);
}

__global__ __launch_bounds__(256) void scan_a(const int* __restrict__ cnt,
        int* __restrict__ bsum) {
    __shared__ int sd[256];
    const int t = threadIdx.x;
    const int base = blockIdx.x * SCAN_CHUNK + t * 8;
    int s = 0;
#pragma unroll
    for (int i = 0; i < 8; ++i) {
        int idx = base + i;
        s += (idx < N_NODES) ? cnt[idx] : 0;
    }
    sd[t] = s; __syncthreads();
    for (int off = 128; off > 0; off >>= 1) {
        if (t < off) sd[t] += sd[t + off];
        __syncthreads();
    }
    if (t == 0) bsum[blockIdx.x] = sd[0];
}

__global__ __launch_bounds__(64) void scan_b(int* __restrict__ bsum,
        int* __restrict__ rowPtr) {
    if (threadIdx.x == 0) {
        int run = 0;
        for (int b = 0; b < NB_SCAN; ++b) {
            int v = bsum[b];
            bsum[b] = run;   // becomes block offset
            run += v;
        }
        rowPtr[N_NODES] = run;
    }
}

__global__ __launch_bounds__(256) void scan_c(const int* __restrict__ cnt,
        const int* __restrict__ boff, int* __restrict__ rowPtr) {
    __shared__ int sd[256];
    const int t = threadIdx.x;
    const int base = blockIdx.x * SCAN_CHUNK + t * 8;
    int v[8];
    int s = 0;
#pragma unroll
    for (int i = 0; i < 8; ++i) {
        int idx = base + i;
        v[i] = (idx < N_NODES) ? cnt[idx] : 0;
        s += v[i];
    }
    sd[t] = s; __syncthreads();
    for (int off = 1; off < 256; off <<= 1) {
        int add = (t >= off) ? sd[t - off] : 0;
        __syncthreads();
        sd[t] += add;
        __syncthreads();
    }
    int run = boff[blockIdx.x] + (sd[t] - s);  // exclusive prefix for this thread
#pragma unroll
    for (int i = 0; i < 8; ++i) {
        int idx = base + i;
        if (idx < N_NODES) rowPtr[idx] = run;
        run += v[i];
    }
}

__global__ __launch_bounds__(256) void scatter_kernel(const int* __restrict__ rows,
        const int* __restrict__ cols, const float* __restrict__ vals,
        const int* __restrict__ rowPtr, int* __restrict__ fill,
        int* __restrict__ colS, float* __restrict__ valS) {
    int e = blockIdx.x * 256 + threadIdx.x;
    if (e < NEDGE) {
        int r = rows[e];
        int p = rowPtr[r] + atomicAdd(&fill[r], 1);
        colS[p] = cols[e];
        valS[p] = vals[e];
    }
}

// ---------------- SpMM (CSR, one wave per row, lane = feature col) ----------------
__global__ __launch_bounds__(256) void spmm64_kernel(const int* __restrict__ colS,
        const float* __restrict__ valS, const int* __restrict__ rowPtr,
        const float* __restrict__ src, float* __restrict__ dst) {
    const int lane = threadIdx.x & 63;
    const int row  = (int)((blockIdx.x * 256u + threadIdx.x) >> 6);
    const int beg = rowPtr[row], end = rowPtr[row + 1];
    float acc = 0.f;
    int i = beg;
    for (; i + 8 <= end; i += 8) {
        int   c[8]; float v[8]; float g[8];
#pragma unroll
        for (int j = 0; j < 8; ++j) { c[j] = colS[i+j]; v[j] = valS[i+j]; }
#pragma unroll
        for (int j = 0; j < 8; ++j) g[j] = src[(size_t)c[j]*HID + lane];
#pragma unroll
        for (int j = 0; j < 8; ++j) acc += v[j]*g[j];
    }
    for (; i < end; ++i)
        acc += valS[i] * src[(size_t)colS[i]*HID + lane];
    dst[(size_t)row*HID + lane] = acc;
}

// t = adj@s fused with r1cat = relu(concat[s-r0, t-s-r0])
__global__ __launch_bounds__(256) void spmm64f_kernel(const int* __restrict__ colS,
        const float* __restrict__ valS, const int* __restrict__ rowPtr,
        const float* __restrict__ s, const float* __restrict__ r0,
        float* __restrict__ r1c) {
    const int lane = threadIdx.x & 63;
    const int row  = (int)((blockIdx.x * 256u + threadIdx.x) >> 6);
    const int beg = rowPtr[row], end = rowPtr[row + 1];
    float acc = 0.f;
    int i = beg;
    for (; i + 8 <= end; i += 8) {
        int   c[8]; float v[8]; float g[8];
#pragma unroll
        for (int j = 0; j < 8; ++j) { c[j] = colS[i+j]; v[j] = valS[i+j]; }
#pragma unroll
        for (int j = 0; j < 8; ++j) g[j] = s[(size_t)c[j]*HID + lane];
#pragma unroll
        for (int j = 0; j < 8; ++j) acc += v[j]*g[j];
    }
    for (; i < end; ++i)
        acc += valS[i] * s[(size_t)colS[i]*HID + lane];
    float sv = s[(size_t)row*HID + lane];
    float rv = r0[(size_t)row*HID + lane];
    r1c[(size_t)row*128 + lane]      = fmaxf(sv - rv, 0.f);
    r1c[(size_t)row*128 + 64 + lane] = fmaxf(acc - sv - rv, 0.f);
}

__global__ __launch_bounds__(256) void spmm128_kernel(const int* __restrict__ colS,
        const float* __restrict__ valS, const int* __restrict__ rowPtr,
        const float* __restrict__ src, float* __restrict__ dst) {
    const int lane = threadIdx.x & 63;
    const int row  = (int)((blockIdx.x * 256u + threadIdx.x) >> 6);
    const int beg = rowPtr[row], end = rowPtr[row + 1];
    float a0 = 0.f, a1 = 0.f;
    int i = beg;
    for (; i + 4 <= end; i += 4) {
        int c[4]; float v[4]; float g0[4], g1[4];
#pragma unroll
        for (int j = 0; j < 4; ++j) { c[j] = colS[i+j]; v[j] = valS[i+j]; }
#pragma unroll
        for (int j = 0; j < 4; ++j) {
            const float* sp = src + (size_t)c[j] * 128;
            g0[j] = sp[lane]; g1[j] = sp[64 + lane];
        }
#pragma unroll
        for (int j = 0; j < 4; ++j) { a0 += v[j]*g0[j]; a1 += v[j]*g1[j]; }
    }
    for (; i < end; ++i) {
        int c = colS[i]; float v = valS[i];
        a0 += v * src[(size_t)c*128 + lane];
        a1 += v * src[(size_t)c*128 + 64 + lane];
    }
    dst[(size_t)row*128 + lane]      = a0;
    dst[(size_t)row*128 + 64 + lane] = a1;
}

// t2 = adj@s2 fused with r2cat = relu(concat[s2-r1, t2-s2-r1])  (widths 128 -> 256)
__global__ __launch_bounds__(256) void spmm128f_kernel(const int* __restrict__ colS,
        const float* __restrict__ valS, const int* __restrict__ rowPtr,
        const float* __restrict__ s2, const float* __restrict__ r1,
        float* __restrict__ r2c) {
    const int lane = threadIdx.x & 63;
    const int row  = (int)((blockIdx.x * 256u + threadIdx.x) >> 6);
    const int beg = rowPtr[row], end = rowPtr[row + 1];
    float a0 = 0.f, a1 = 0.f;
    int i = beg;
    for (; i + 4 <= end; i += 4) {
        int c[4]; float v[4]; float g0[4], g1[4];
#pragma unroll
        for (int j = 0; j < 4; ++j) { c[j] = colS[i+j]; v[j] = valS[i+j]; }
#pragma unroll
        for (int j = 0; j < 4; ++j) {
            const float* sp = s2 + (size_t)c[j] * 128;
            g0[j] = sp[lane]; g1[j] = sp[64 + lane];
        }
#pragma unroll
        for (int j = 0; j < 4; ++j) { a0 += v[j]*g0[j]; a1 += v[j]*g1[j]; }
    }
    for (; i < end; ++i) {
        int c = colS[i]; float v = valS[i];
        a0 += v * s2[(size_t)c*128 + lane];
        a1 += v * s2[(size_t)c*128 + 64 + lane];
    }
    float s0v = s2[(size_t)row*128 + lane];
    float s1v = s2[(size_t)row*128 + 64 + lane];
    float r0v = r1[(size_t)row*128 + lane];
    float r1v = r1[(size_t)row*128 + 64 + lane];
    size_t ob = (size_t)row * 256 + lane;
    r2c[ob]        = fmaxf(s0v - r0v, 0.f);
    r2c[ob + 64]   = fmaxf(s1v - r1v, 0.f);
    r2c[ob + 128]  = fmaxf(a0 - s0v - r0v, 0.f);
    r2c[ob + 192]  = fmaxf(a1 - s1v - r1v, 0.f);
}

// ---------------- tiled GEMM: classify + softmax ----------------
// virtual concat [r0(64) | r1cat(128) | r2cat(256)] @ Wc[448,64], then row softmax.
// BM=64, BN=64, BK=16; 256 threads = 4 waves; grid NPAD/64 = 782.
__global__ __launch_bounds__(256, 4) void classify_kernel(const float* __restrict__ r0,
        const float* __restrict__ r1, const float* __restrict__ r2,
        const float* __restrict__ wc, float* __restrict__ out) {
    __shared__ float lds_a[64 * 16];
    __shared__ float lds_w[16 * 64];
    const int t    = threadIdx.x;
    const int lane = t & 63;
    const int wv   = t >> 6;
    const int row0 = blockIdx.x * 64;
    const int srow = t >> 2;
    const int scol = (t & 3) * 4;
    const int wrow = t >> 4;
    const int wcol = (t & 15) * 4;

    float acc[16];
#pragma unroll
    for (int r = 0; r < 16; ++r) acc[r] = 0.f;

    auto load_act = [&](int kt) -> float4 {
        const float* seg; int stride; int kof;
        if (kt < 64)       { seg = r0; stride = 64;  kof = kt; }
        else if (kt < 192) { seg = r1; stride = 128; kof = kt - 64; }
        else               { seg = r2; stride = 256; kof = kt - 192; }
        return *(const float4*)(seg + (size_t)(row0 + srow) * stride + kof + scol);
    };

    float4 pa = load_act(0);
    float4 pw = *(const float4*)(wc + (size_t)wrow * 64 + wcol);
    *(float4*)&lds_a[srow * 16 + scol] = pa;
    *(float4*)&lds_w[wrow * 64 + wcol] = pw;
    __syncthreads();

    const int NSTEP = 28;  // 448/16
    for (int step = 0; step < NSTEP; ++step) {
        if (step + 1 < NSTEP) {
            int kt = (step + 1) * 16;
            pa = load_act(kt);
            pw = *(const float4*)(wc + (size_t)(kt + wrow) * 64 + wcol);
        }
#pragma unroll
        for (int kk4 = 0; kk4 < 4; ++kk4) {
            float w0 = lds_w[(kk4 * 4 + 0) * 64 + lane];
            float w1 = lds_w[(kk4 * 4 + 1) * 64 + lane];
            float w2 = lds_w[(kk4 * 4 + 2) * 64 + lane];
            float w3 = lds_w[(kk4 * 4 + 3) * 64 + lane];
#pragma unroll
            for (int rr = 0; rr < 16; ++rr) {
                float4 a4 = *(const float4*)&lds_a[(wv * 16 + rr) * 16 + kk4 * 4];
                acc[rr] += a4.x * w0 + a4.y * w1 + a4.z * w2 + a4.w * w3;
            }
        }
        __syncthreads();
        if (step + 1 < NSTEP) {
            *(float4*)&lds_a[srow * 16 + scol] = pa;
            *(float4*)&lds_w[wrow * 64 + wcol] = pw;
        }
        __syncthreads();
    }

#pragma unroll
    for (int rr = 0; rr < 16; ++rr) {
        float m = acc[rr];
        for (int o = 32; o > 0; o >>= 1) m = fmaxf(m, __shfl_xor(m, o));
        float e = __expf(acc[rr] - m);
        float ssum = e;
        for (int o = 32; o > 0; o >>= 1) ssum += __shfl_xor(ssum, o);
        int rv = row0 + wv * 16 + rr;
        if (rv < N_NODES)
            out[(size_t)rv * 64 + lane] = e / ssum;
    }
}

extern "C" void kernel_launch(void* const* d_in, const int* in_sizes, int n_in,
                              void* d_out, int out_size, void* d_ws, size_t ws_size,
                              hipStream_t stream) {
    const float* x    = (const float*)d_in[0];
    const int*   erow = (const int*)d_in[1];
    const int*   ecol = (const int*)d_in[2];
    const float* eval = (const float*)d_in[3];
    const float* we   = (const float*)d_in[4];
    const float* wc   = (const float*)d_in[5];
    float* out = (float*)d_out;

    char* w = (char*)d_ws;
    size_t off = 0;
    auto take = [&](size_t bytes) {
        char* p = w + off;
        off += (bytes + 255) & ~(size_t)255;
        return p;
    };
    // padded to NPAD rows so 64-row tiles can read past 50000 safely
    float* r0     = (float*)take((size_t)NPAD * 64 * 4);
    float* sbuf   = (float*)take((size_t)NPAD * 128 * 4);  // s (w64) then s2 (w128)
    float* r1c    = (float*)take((size_t)NPAD * 128 * 4);
    float* r2c    = (float*)take((size_t)NPAD * 256 * 4);
    int*   cnt    = (int*)take((size_t)N_NODES * 4);
    int*   rowPtr = (int*)take((size_t)(N_NODES + 1) * 4);
    int*   fill   = (int*)take((size_t)N_NODES * 4);
    int*   bsum   = (int*)take((size_t)NB_SCAN * 4);
    int*   colS   = (int*)take((size_t)NEDGE * 4);
    float* valS   = (float*)take((size_t)NEDGE * 4);
    (void)ws_size; (void)in_sizes; (void)n_in; (void)out_size;

    hipMemsetAsync(cnt,  0, (size_t)N_NODES * 4, stream);
    hipMemsetAsync(fill, 0, (size_t)N_NODES * 4, stream);

    embed_kernel<<<NPAD / 64, 256, 0, stream>>>(x, we, r0);

    hist_kernel<<<3125, 256, 0, stream>>>(erow, cnt);
    scan_a<<<NB_SCAN, 256, 0, stream>>>(cnt, bsum);
    scan_b<<<1, 64, 0, stream>>>(bsum, rowPtr);
    scan_c<<<NB_SCAN, 256, 0, stream>>>(cnt, bsum, rowPtr);
    scatter_kernel<<<3125, 256, 0, stream>>>(erow, ecol, eval, rowPtr, fill, colS, valS);

    spmm64_kernel <<<12500, 256, 0, stream>>>(colS, valS, rowPtr, r0, sbuf);
    spmm64f_kernel<<<12500, 256, 0, stream>>>(colS, valS, rowPtr, sbuf, r0, r1c);
    spmm128_kernel<<<12500, 256, 0, stream>>>(colS, valS, rowPtr, r1c, sbuf);
    spmm128f_kernel<<<12500, 256, 0, stream>>>(colS, valS, rowPtr, sbuf, r1c, r2c);

    classify_kernel<<<NPAD / 64, 256, 0, stream>>>(r0, r1c, r2c, wc, out);
}

// Round 5
// 572.187 us; speedup vs baseline: 3.0208x; 3.0208x over previous
//
#include <hip/hip_runtime.h>

#define N_NODES 50000
#define NPAD 50048            // padded row count (multiple of 64)
#define FEAT 256
#define HID 64
#define NEDGE 800000
#define SCAN_CHUNK 2048
#define NB_SCAN 25  // ceil(50000/2048)

// ---------------- tiled GEMM: embed  r0 = relu(x @ We) ----------------
// BM=64 rows/block, BN=64 (full), BK=16. 256 threads = 4 waves.
// lane = output col; wave w owns rows w*16..w*16+15 (acc[16]).
// Double-buffered LDS, one barrier per k-step; a4 consumed immediately
// after read (avoid R4's 16-live-float4 spill catastrophe).
__global__ __launch_bounds__(256) void embed_kernel(const float* __restrict__ x,
        const float* __restrict__ we, float* __restrict__ r0) {
    __shared__ float lds_a[2][64 * 16];
    __shared__ float lds_w[2][16 * 64];
    const int t    = threadIdx.x;
    const int lane = t & 63;
    const int wv   = t >> 6;
    const int row0 = blockIdx.x * 64;
    const int srow = t >> 2;          // 0..63  (act stage row)
    const int scol = (t & 3) * 4;     // 0,4,8,12
    const int wrow = t >> 4;          // 0..15  (weight stage k-row)
    const int wcol = (t & 15) * 4;

    const int asrc = (row0 + srow < N_NODES) ? (row0 + srow) : (N_NODES - 1);

    float acc[16];
#pragma unroll
    for (int r = 0; r < 16; ++r) acc[r] = 0.f;

    // prologue: stage tile 0 into buffer 0
    {
        float4 pa = *(const float4*)(x + (size_t)asrc * FEAT + scol);
        float4 pw = *(const float4*)(we + (size_t)wrow * 64 + wcol);
        *(float4*)&lds_a[0][srow * 16 + scol] = pa;
        *(float4*)&lds_w[0][wrow * 64 + wcol] = pw;
    }
    __syncthreads();

    const int NSTEP = FEAT / 16;  // 16
    for (int step = 0; step < NSTEP; ++step) {
        const int cur = step & 1;
        float4 pa, pw;
        const bool more = (step + 1 < NSTEP);
        if (more) {   // issue next-tile global loads early (hide under compute)
            int kt = (step + 1) * 16;
            pa = *(const float4*)(x + (size_t)asrc * FEAT + kt + scol);
            pw = *(const float4*)(we + (size_t)(kt + wrow) * 64 + wcol);
        }
#pragma unroll
        for (int kk4 = 0; kk4 < 4; ++kk4) {
            float w0 = lds_w[cur][(kk4 * 4 + 0) * 64 + lane];
            float w1 = lds_w[cur][(kk4 * 4 + 1) * 64 + lane];
            float w2 = lds_w[cur][(kk4 * 4 + 2) * 64 + lane];
            float w3 = lds_w[cur][(kk4 * 4 + 3) * 64 + lane];
#pragma unroll
            for (int rr = 0; rr < 16; ++rr) {
                float4 a4 = *(const float4*)&lds_a[cur][(wv * 16 + rr) * 16 + kk4 * 4];
                acc[rr] += a4.x * w0 + a4.y * w1 + a4.z * w2 + a4.w * w3;
            }
        }
        if (more) {
            *(float4*)&lds_a[cur ^ 1][srow * 16 + scol] = pa;
            *(float4*)&lds_w[cur ^ 1][wrow * 64 + wcol] = pw;
        }
        __syncthreads();
    }

#pragma unroll
    for (int rr = 0; rr < 16; ++rr) {
        int rv = row0 + wv * 16 + rr;
        if (rv < N_NODES)
            r0[(size_t)rv * HID + lane] = fmaxf(acc[rr], 0.f);
    }
}

// ---------------- CSR build ----------------
__global__ __launch_bounds__(256) void hist_kernel(const int* __restrict__ rows,
        int* __restrict__ cnt) {
    int e = blockIdx.x * 256 + threadIdx.x;
    if (e < NEDGE) atomicAdd(&cnt[rows[e]], 1);
}

__global__ __launch_bounds__(256) void scan_a(const int* __restrict__ cnt,
        int* __restrict__ bsum) {
    __shared__ int sd[256];
    const int t = threadIdx.x;
    const int base = blockIdx.x * SCAN_CHUNK + t * 8;
    int s = 0;
#pragma unroll
    for (int i = 0; i < 8; ++i) {
        int idx = base + i;
        s += (idx < N_NODES) ? cnt[idx] : 0;
    }
    sd[t] = s; __syncthreads();
    for (int off = 128; off > 0; off >>= 1) {
        if (t < off) sd[t] += sd[t + off];
        __syncthreads();
    }
    if (t == 0) bsum[blockIdx.x] = sd[0];
}

__global__ __launch_bounds__(64) void scan_b(int* __restrict__ bsum,
        int* __restrict__ rowPtr) {
    if (threadIdx.x == 0) {
        int run = 0;
        for (int b = 0; b < NB_SCAN; ++b) {
            int v = bsum[b];
            bsum[b] = run;   // becomes block offset
            run += v;
        }
        rowPtr[N_NODES] = run;
    }
}

__global__ __launch_bounds__(256) void scan_c(const int* __restrict__ cnt,
        const int* __restrict__ boff, int* __restrict__ rowPtr) {
    __shared__ int sd[256];
    const int t = threadIdx.x;
    const int base = blockIdx.x * SCAN_CHUNK + t * 8;
    int v[8];
    int s = 0;
#pragma unroll
    for (int i = 0; i < 8; ++i) {
        int idx = base + i;
        v[i] = (idx < N_NODES) ? cnt[idx] : 0;
        s += v[i];
    }
    sd[t] = s; __syncthreads();
    for (int off = 1; off < 256; off <<= 1) {
        int add = (t >= off) ? sd[t - off] : 0;
        __syncthreads();
        sd[t] += add;
        __syncthreads();
    }
    int run = boff[blockIdx.x] + (sd[t] - s);  // exclusive prefix for this thread
#pragma unroll
    for (int i = 0; i < 8; ++i) {
        int idx = base + i;
        if (idx < N_NODES) rowPtr[idx] = run;
        run += v[i];
    }
}

__global__ __launch_bounds__(256) void scatter_kernel(const int* __restrict__ rows,
        const int* __restrict__ cols, const float* __restrict__ vals,
        const int* __restrict__ rowPtr, int* __restrict__ fill,
        int* __restrict__ colS, float* __restrict__ valS) {
    int e = blockIdx.x * 256 + threadIdx.x;
    if (e < NEDGE) {
        int r = rows[e];
        int p = rowPtr[r] + atomicAdd(&fill[r], 1);
        colS[p] = cols[e];
        valS[p] = vals[e];
    }
}

// ---------------- SpMM (CSR, one wave per row, lane = feature col) ----------------
__global__ __launch_bounds__(256) void spmm64_kernel(const int* __restrict__ colS,
        const float* __restrict__ valS, const int* __restrict__ rowPtr,
        const float* __restrict__ src, float* __restrict__ dst) {
    const int lane = threadIdx.x & 63;
    const int row  = (int)((blockIdx.x * 256u + threadIdx.x) >> 6);
    const int beg = rowPtr[row], end = rowPtr[row + 1];
    float acc = 0.f;
    int i = beg;
    for (; i + 8 <= end; i += 8) {
        int   c[8]; float v[8]; float g[8];
#pragma unroll
        for (int j = 0; j < 8; ++j) { c[j] = colS[i+j]; v[j] = valS[i+j]; }
#pragma unroll
        for (int j = 0; j < 8; ++j) g[j] = src[(size_t)c[j]*HID + lane];
#pragma unroll
        for (int j = 0; j < 8; ++j) acc += v[j]*g[j];
    }
    for (; i < end; ++i)
        acc += valS[i] * src[(size_t)colS[i]*HID + lane];
    dst[(size_t)row*HID + lane] = acc;
}

// t = adj@s fused with r1cat = relu(concat[s-r0, t-s-r0])
__global__ __launch_bounds__(256) void spmm64f_kernel(const int* __restrict__ colS,
        const float* __restrict__ valS, const int* __restrict__ rowPtr,
        const float* __restrict__ s, const float* __restrict__ r0,
        float* __restrict__ r1c) {
    const int lane = threadIdx.x & 63;
    const int row  = (int)((blockIdx.x * 256u + threadIdx.x) >> 6);
    const int beg = rowPtr[row], end = rowPtr[row + 1];
    float acc = 0.f;
    int i = beg;
    for (; i + 8 <= end; i += 8) {
        int   c[8]; float v[8]; float g[8];
#pragma unroll
        for (int j = 0; j < 8; ++j) { c[j] = colS[i+j]; v[j] = valS[i+j]; }
#pragma unroll
        for (int j = 0; j < 8; ++j) g[j] = s[(size_t)c[j]*HID + lane];
#pragma unroll
        for (int j = 0; j < 8; ++j) acc += v[j]*g[j];
    }
    for (; i < end; ++i)
        acc += valS[i] * s[(size_t)colS[i]*HID + lane];
    float sv = s[(size_t)row*HID + lane];
    float rv = r0[(size_t)row*HID + lane];
    r1c[(size_t)row*128 + lane]      = fmaxf(sv - rv, 0.f);
    r1c[(size_t)row*128 + 64 + lane] = fmaxf(acc - sv - rv, 0.f);
}

__global__ __launch_bounds__(256) void spmm128_kernel(const int* __restrict__ colS,
        const float* __restrict__ valS, const int* __restrict__ rowPtr,
        const float* __restrict__ src, float* __restrict__ dst) {
    const int lane = threadIdx.x & 63;
    const int row  = (int)((blockIdx.x * 256u + threadIdx.x) >> 6);
    const int beg = rowPtr[row], end = rowPtr[row + 1];
    float a0 = 0.f, a1 = 0.f;
    int i = beg;
    for (; i + 4 <= end; i += 4) {
        int c[4]; float v[4]; float g0[4], g1[4];
#pragma unroll
        for (int j = 0; j < 4; ++j) { c[j] = colS[i+j]; v[j] = valS[i+j]; }
#pragma unroll
        for (int j = 0; j < 4; ++j) {
            const float* sp = src + (size_t)c[j] * 128;
            g0[j] = sp[lane]; g1[j] = sp[64 + lane];
        }
#pragma unroll
        for (int j = 0; j < 4; ++j) { a0 += v[j]*g0[j]; a1 += v[j]*g1[j]; }
    }
    for (; i < end; ++i) {
        int c = colS[i]; float v = valS[i];
        a0 += v * src[(size_t)c*128 + lane];
        a1 += v * src[(size_t)c*128 + 64 + lane];
    }
    dst[(size_t)row*128 + lane]      = a0;
    dst[(size_t)row*128 + 64 + lane] = a1;
}

// t2 = adj@s2 fused with r2cat = relu(concat[s2-r1, t2-s2-r1])  (widths 128 -> 256)
__global__ __launch_bounds__(256) void spmm128f_kernel(const int* __restrict__ colS,
        const float* __restrict__ valS, const int* __restrict__ rowPtr,
        const float* __restrict__ s2, const float* __restrict__ r1,
        float* __restrict__ r2c) {
    const int lane = threadIdx.x & 63;
    const int row  = (int)((blockIdx.x * 256u + threadIdx.x) >> 6);
    const int beg = rowPtr[row], end = rowPtr[row + 1];
    float a0 = 0.f, a1 = 0.f;
    int i = beg;
    for (; i + 4 <= end; i += 4) {
        int c[4]; float v[4]; float g0[4], g1[4];
#pragma unroll
        for (int j = 0; j < 4; ++j) { c[j] = colS[i+j]; v[j] = valS[i+j]; }
#pragma unroll
        for (int j = 0; j < 4; ++j) {
            const float* sp = s2 + (size_t)c[j] * 128;
            g0[j] = sp[lane]; g1[j] = sp[64 + lane];
        }
#pragma unroll
        for (int j = 0; j < 4; ++j) { a0 += v[j]*g0[j]; a1 += v[j]*g1[j]; }
    }
    for (; i < end; ++i) {
        int c = colS[i]; float v = valS[i];
        a0 += v * s2[(size_t)c*128 + lane];
        a1 += v * s2[(size_t)c*128 + 64 + lane];
    }
    float s0v = s2[(size_t)row*128 + lane];
    float s1v = s2[(size_t)row*128 + 64 + lane];
    float r0v = r1[(size_t)row*128 + lane];
    float r1v = r1[(size_t)row*128 + 64 + lane];
    size_t ob = (size_t)row * 256 + lane;
    r2c[ob]        = fmaxf(s0v - r0v, 0.f);
    r2c[ob + 64]   = fmaxf(s1v - r1v, 0.f);
    r2c[ob + 128]  = fmaxf(a0 - s0v - r0v, 0.f);
    r2c[ob + 192]  = fmaxf(a1 - s1v - r1v, 0.f);
}

// ---------------- tiled GEMM: classify + softmax ----------------
// virtual concat [r0(64) | r1cat(128) | r2cat(256)] @ Wc[448,64], then row softmax.
// BM=64, BN=64, BK=16; 256 threads = 4 waves; grid NPAD/64 = 782.
// Double-buffered LDS, one barrier per k-step.
__global__ __launch_bounds__(256) void classify_kernel(const float* __restrict__ r0,
        const float* __restrict__ r1, const float* __restrict__ r2,
        const float* __restrict__ wc, float* __restrict__ out) {
    __shared__ float lds_a[2][64 * 16];
    __shared__ float lds_w[2][16 * 64];
    const int t    = threadIdx.x;
    const int lane = t & 63;
    const int wv   = t >> 6;
    const int row0 = blockIdx.x * 64;
    const int srow = t >> 2;
    const int scol = (t & 3) * 4;
    const int wrow = t >> 4;
    const int wcol = (t & 15) * 4;

    float acc[16];
#pragma unroll
    for (int r = 0; r < 16; ++r) acc[r] = 0.f;

    auto load_act = [&](int kt) -> float4 {
        const float* seg; int stride; int kof;
        if (kt < 64)       { seg = r0; stride = 64;  kof = kt; }
        else if (kt < 192) { seg = r1; stride = 128; kof = kt - 64; }
        else               { seg = r2; stride = 256; kof = kt - 192; }
        return *(const float4*)(seg + (size_t)(row0 + srow) * stride + kof + scol);
    };

    {
        float4 pa = load_act(0);
        float4 pw = *(const float4*)(wc + (size_t)wrow * 64 + wcol);
        *(float4*)&lds_a[0][srow * 16 + scol] = pa;
        *(float4*)&lds_w[0][wrow * 64 + wcol] = pw;
    }
    __syncthreads();

    const int NSTEP = 28;  // 448/16
    for (int step = 0; step < NSTEP; ++step) {
        const int cur = step & 1;
        float4 pa, pw;
        const bool more = (step + 1 < NSTEP);
        if (more) {
            int kt = (step + 1) * 16;
            pa = load_act(kt);
            pw = *(const float4*)(wc + (size_t)(kt + wrow) * 64 + wcol);
        }
#pragma unroll
        for (int kk4 = 0; kk4 < 4; ++kk4) {
            float w0 = lds_w[cur][(kk4 * 4 + 0) * 64 + lane];
            float w1 = lds_w[cur][(kk4 * 4 + 1) * 64 + lane];
            float w2 = lds_w[cur][(kk4 * 4 + 2) * 64 + lane];
            float w3 = lds_w[cur][(kk4 * 4 + 3) * 64 + lane];
#pragma unroll
            for (int rr = 0; rr < 16; ++rr) {
                float4 a4 = *(const float4*)&lds_a[cur][(wv * 16 + rr) * 16 + kk4 * 4];
                acc[rr] += a4.x * w0 + a4.y * w1 + a4.z * w2 + a4.w * w3;
            }
        }
        if (more) {
            *(float4*)&lds_a[cur ^ 1][srow * 16 + scol] = pa;
            *(float4*)&lds_w[cur ^ 1][wrow * 64 + wcol] = pw;
        }
        __syncthreads();
    }

#pragma unroll
    for (int rr = 0; rr < 16; ++rr) {
        float m = acc[rr];
        for (int o = 32; o > 0; o >>= 1) m = fmaxf(m, __shfl_xor(m, o));
        float e = __expf(acc[rr] - m);
        float ssum = e;
        for (int o = 32; o > 0; o >>= 1) ssum += __shfl_xor(ssum, o);
        int rv = row0 + wv * 16 + rr;
        if (rv < N_NODES)
            out[(size_t)rv * 64 + lane] = e / ssum;
    }
}

extern "C" void kernel_launch(void* const* d_in, const int* in_sizes, int n_in,
                              void* d_out, int out_size, void* d_ws, size_t ws_size,
                              hipStream_t stream) {
    const float* x    = (const float*)d_in[0];
    const int*   erow = (const int*)d_in[1];
    const int*   ecol = (const int*)d_in[2];
    const float* eval = (const float*)d_in[3];
    const float* we   = (const float*)d_in[4];
    const float* wc   = (const float*)d_in[5];
    float* out = (float*)d_out;

    char* w = (char*)d_ws;
    size_t off = 0;
    auto take = [&](size_t bytes) {
        char* p = w + off;
        off += (bytes + 255) & ~(size_t)255;
        return p;
    };
    // padded to NPAD rows so 64-row tiles can read past 50000 safely
    float* r0     = (float*)take((size_t)NPAD * 64 * 4);
    float* sbuf   = (float*)take((size_t)NPAD * 128 * 4);  // s (w64) then s2 (w128)
    float* r1c    = (float*)take((size_t)NPAD * 128 * 4);
    float* r2c    = (float*)take((size_t)NPAD * 256 * 4);
    int*   cnt    = (int*)take((size_t)N_NODES * 4);
    int*   rowPtr = (int*)take((size_t)(N_NODES + 1) * 4);
    int*   fill   = (int*)take((size_t)N_NODES * 4);
    int*   bsum   = (int*)take((size_t)NB_SCAN * 4);
    int*   colS   = (int*)take((size_t)NEDGE * 4);
    float* valS   = (float*)take((size_t)NEDGE * 4);
    (void)ws_size; (void)in_sizes; (void)n_in; (void)out_size;

    hipMemsetAsync(cnt,  0, (size_t)N_NODES * 4, stream);
    hipMemsetAsync(fill, 0, (size_t)N_NODES * 4, stream);

    embed_kernel<<<NPAD / 64, 256, 0, stream>>>(x, we, r0);

    hist_kernel<<<3125, 256, 0, stream>>>(erow, cnt);
    scan_a<<<NB_SCAN, 256, 0, stream>>>(cnt, bsum);
    scan_b<<<1, 64, 0, stream>>>(bsum, rowPtr);
    scan_c<<<NB_SCAN, 256, 0, stream>>>(cnt, bsum, rowPtr);
    scatter_kernel<<<3125, 256, 0, stream>>>(erow, ecol, eval, rowPtr, fill, colS, valS);

    spmm64_kernel <<<12500, 256, 0, stream>>>(colS, valS, rowPtr, r0, sbuf);
    spmm64f_kernel<<<12500, 256, 0, stream>>>(colS, valS, rowPtr, sbuf, r0, r1c);
    spmm128_kernel<<<12500, 256, 0, stream>>>(colS, valS, rowPtr, r1c, sbuf);
    spmm128f_kernel<<<12500, 256, 0, stream>>>(colS, valS, rowPtr, sbuf, r1c, r2c);

    classify_kernel<<<NPAD / 64, 256, 0, stream>>>(r0, r1c, r2c, wc, out);
}

// Round 6
// 408.752 us; speedup vs baseline: 4.2287x; 1.3998x over previous
//
#include <hip/hip_runtime.h>

#define N_NODES 50000
#define NPAD 50048            // padded row count (multiple of 128)
#define FEAT 256
#define HID 64
#define NEDGE 800000
#define SCAN_CHUNK 2048
#define NB_SCAN 25  // ceil(50000/2048)
#define APAD 132              // A-tile LDS leading pad (k-major [16][APAD])

// ================= tiled GEMM common structure =================
// BM=128, BN=64, BK=16, 256 threads (4 waves). Thread (g = t>>4, q = t&15)
// owns C micro-tile rows m0=g*8..+7, cols n0=q*4..+3  (acc[8][4]).
// A staged transposed (k-major, pad APAD) so av reads are b128 row-slices;
// W staged [k][n]. Double-buffered LDS; global prefetch issued before compute.

// ---------------- embed: r0 = relu(x @ We)  [50000,256]@[256,64] ----------------
__global__ __launch_bounds__(256) void embed_kernel(const float* __restrict__ x,
        const float* __restrict__ we, float* __restrict__ r0) {
    __shared__ float lds_a[2][16 * APAD];
    __shared__ float lds_w[2][16 * 64];
    const int t    = threadIdx.x;
    const int row0 = blockIdx.x * 128;
    const int m0   = (t >> 4) * 8;
    const int n0   = (t & 15) * 4;
    const int srow = t >> 1;          // 0..127 (A stage row)
    const int kk   = (t & 1) * 8;     // 0 or 8 (A stage k-chunk)
    const int wrow = t >> 4;          // 0..15
    const int wcol = (t & 15) * 4;

    int ar = row0 + srow;
    if (ar >= N_NODES) ar = N_NODES - 1;   // x has exactly N_NODES rows
    const float* axp = x + (size_t)ar * FEAT + kk;

    float acc[8][4];
#pragma unroll
    for (int i = 0; i < 8; ++i)
#pragma unroll
        for (int j = 0; j < 4; ++j) acc[i][j] = 0.f;

    {   // prologue: stage k-tile 0 into buffer 0
        float4 v0 = *(const float4*)(axp + 0);
        float4 v1 = *(const float4*)(axp + 4);
        float4 pw = *(const float4*)(we + (size_t)wrow * 64 + wcol);
        lds_a[0][(kk+0)*APAD + srow] = v0.x;
        lds_a[0][(kk+1)*APAD + srow] = v0.y;
        lds_a[0][(kk+2)*APAD + srow] = v0.z;
        lds_a[0][(kk+3)*APAD + srow] = v0.w;
        lds_a[0][(kk+4)*APAD + srow] = v1.x;
        lds_a[0][(kk+5)*APAD + srow] = v1.y;
        lds_a[0][(kk+6)*APAD + srow] = v1.z;
        lds_a[0][(kk+7)*APAD + srow] = v1.w;
        *(float4*)&lds_w[0][wrow * 64 + wcol] = pw;
    }
    __syncthreads();

    const int NSTEP = FEAT / 16;  // 16
    for (int step = 0; step < NSTEP; ++step) {
        const int cur = step & 1;
        const bool more = (step + 1 < NSTEP);
        float4 v0, v1, pw;
        if (more) {   // issue next-tile global loads early
            int kt = (step + 1) * 16;
            v0 = *(const float4*)(axp + kt);
            v1 = *(const float4*)(axp + kt + 4);
            pw = *(const float4*)(we + (size_t)(kt + wrow) * 64 + wcol);
        }
#pragma unroll
        for (int k = 0; k < 16; ++k) {
            float4 a0 = *(const float4*)&lds_a[cur][k * APAD + m0];
            float4 a1 = *(const float4*)&lds_a[cur][k * APAD + m0 + 4];
            float4 wv = *(const float4*)&lds_w[cur][k * 64 + n0];
            float aa[8] = {a0.x,a0.y,a0.z,a0.w,a1.x,a1.y,a1.z,a1.w};
            float ww[4] = {wv.x,wv.y,wv.z,wv.w};
#pragma unroll
            for (int i = 0; i < 8; ++i)
#pragma unroll
                for (int j = 0; j < 4; ++j) acc[i][j] += aa[i] * ww[j];
        }
        if (more) {
            const int nb = cur ^ 1;
            lds_a[nb][(kk+0)*APAD + srow] = v0.x;
            lds_a[nb][(kk+1)*APAD + srow] = v0.y;
            lds_a[nb][(kk+2)*APAD + srow] = v0.z;
            lds_a[nb][(kk+3)*APAD + srow] = v0.w;
            lds_a[nb][(kk+4)*APAD + srow] = v1.x;
            lds_a[nb][(kk+5)*APAD + srow] = v1.y;
            lds_a[nb][(kk+6)*APAD + srow] = v1.z;
            lds_a[nb][(kk+7)*APAD + srow] = v1.w;
            *(float4*)&lds_w[nb][wrow * 64 + wcol] = pw;
        }
        __syncthreads();
    }

#pragma unroll
    for (int i = 0; i < 8; ++i) {
        int rv = row0 + m0 + i;
        if (rv < N_NODES) {
            float4 o;
            o.x = fmaxf(acc[i][0], 0.f);
            o.y = fmaxf(acc[i][1], 0.f);
            o.z = fmaxf(acc[i][2], 0.f);
            o.w = fmaxf(acc[i][3], 0.f);
            *(float4*)(r0 + (size_t)rv * HID + n0) = o;
        }
    }
}

// ---------------- CSR build ----------------
__global__ __launch_bounds__(256) void hist_kernel(const int* __restrict__ rows,
        int* __restrict__ cnt) {
    int e = blockIdx.x * 256 + threadIdx.x;
    if (e < NEDGE) atomicAdd(&cnt[rows[e]], 1);
}

__global__ __launch_bounds__(256) void scan_a(const int* __restrict__ cnt,
        int* __restrict__ bsum) {
    __shared__ int sd[256];
    const int t = threadIdx.x;
    const int base = blockIdx.x * SCAN_CHUNK + t * 8;
    int s = 0;
#pragma unroll
    for (int i = 0; i < 8; ++i) {
        int idx = base + i;
        s += (idx < N_NODES) ? cnt[idx] : 0;
    }
    sd[t] = s; __syncthreads();
    for (int off = 128; off > 0; off >>= 1) {
        if (t < off) sd[t] += sd[t + off];
        __syncthreads();
    }
    if (t == 0) bsum[blockIdx.x] = sd[0];
}

__global__ __launch_bounds__(64) void scan_b(int* __restrict__ bsum,
        int* __restrict__ rowPtr) {
    if (threadIdx.x == 0) {
        int run = 0;
        for (int b = 0; b < NB_SCAN; ++b) {
            int v = bsum[b];
            bsum[b] = run;   // becomes block offset
            run += v;
        }
        rowPtr[N_NODES] = run;
    }
}

__global__ __launch_bounds__(256) void scan_c(const int* __restrict__ cnt,
        const int* __restrict__ boff, int* __restrict__ rowPtr) {
    __shared__ int sd[256];
    const int t = threadIdx.x;
    const int base = blockIdx.x * SCAN_CHUNK + t * 8;
    int v[8];
    int s = 0;
#pragma unroll
    for (int i = 0; i < 8; ++i) {
        int idx = base + i;
        v[i] = (idx < N_NODES) ? cnt[idx] : 0;
        s += v[i];
    }
    sd[t] = s; __syncthreads();
    for (int off = 1; off < 256; off <<= 1) {
        int add = (t >= off) ? sd[t - off] : 0;
        __syncthreads();
        sd[t] += add;
        __syncthreads();
    }
    int run = boff[blockIdx.x] + (sd[t] - s);  // exclusive prefix for this thread
#pragma unroll
    for (int i = 0; i < 8; ++i) {
        int idx = base + i;
        if (idx < N_NODES) rowPtr[idx] = run;
        run += v[i];
    }
}

__global__ __launch_bounds__(256) void scatter_kernel(const int* __restrict__ rows,
        const int* __restrict__ cols, const float* __restrict__ vals,
        const int* __restrict__ rowPtr, int* __restrict__ fill,
        int* __restrict__ colS, float* __restrict__ valS) {
    int e = blockIdx.x * 256 + threadIdx.x;
    if (e < NEDGE) {
        int r = rows[e];
        int p = rowPtr[r] + atomicAdd(&fill[r], 1);
        colS[p] = cols[e];
        valS[p] = vals[e];
    }
}

// ---------------- SpMM (CSR, one wave per row, lane = feature col) ----------------
__global__ __launch_bounds__(256) void spmm64_kernel(const int* __restrict__ colS,
        const float* __restrict__ valS, const int* __restrict__ rowPtr,
        const float* __restrict__ src, float* __restrict__ dst) {
    const int lane = threadIdx.x & 63;
    const int row  = (int)((blockIdx.x * 256u + threadIdx.x) >> 6);
    const int beg = rowPtr[row], end = rowPtr[row + 1];
    float acc = 0.f;
    int i = beg;
    for (; i + 8 <= end; i += 8) {
        int   c[8]; float v[8]; float g[8];
#pragma unroll
        for (int j = 0; j < 8; ++j) { c[j] = colS[i+j]; v[j] = valS[i+j]; }
#pragma unroll
        for (int j = 0; j < 8; ++j) g[j] = src[(size_t)c[j]*HID + lane];
#pragma unroll
        for (int j = 0; j < 8; ++j) acc += v[j]*g[j];
    }
    for (; i < end; ++i)
        acc += valS[i] * src[(size_t)colS[i]*HID + lane];
    dst[(size_t)row*HID + lane] = acc;
}

// t = adj@s fused with r1cat = relu(concat[s-r0, t-s-r0])
__global__ __launch_bounds__(256) void spmm64f_kernel(const int* __restrict__ colS,
        const float* __restrict__ valS, const int* __restrict__ rowPtr,
        const float* __restrict__ s, const float* __restrict__ r0,
        float* __restrict__ r1c) {
    const int lane = threadIdx.x & 63;
    const int row  = (int)((blockIdx.x * 256u + threadIdx.x) >> 6);
    const int beg = rowPtr[row], end = rowPtr[row + 1];
    float acc = 0.f;
    int i = beg;
    for (; i + 8 <= end; i += 8) {
        int   c[8]; float v[8]; float g[8];
#pragma unroll
        for (int j = 0; j < 8; ++j) { c[j] = colS[i+j]; v[j] = valS[i+j]; }
#pragma unroll
        for (int j = 0; j < 8; ++j) g[j] = s[(size_t)c[j]*HID + lane];
#pragma unroll
        for (int j = 0; j < 8; ++j) acc += v[j]*g[j];
    }
    for (; i < end; ++i)
        acc += valS[i] * s[(size_t)colS[i]*HID + lane];
    float sv = s[(size_t)row*HID + lane];
    float rv = r0[(size_t)row*HID + lane];
    r1c[(size_t)row*128 + lane]      = fmaxf(sv - rv, 0.f);
    r1c[(size_t)row*128 + 64 + lane] = fmaxf(acc - sv - rv, 0.f);
}

__global__ __launch_bounds__(256) void spmm128_kernel(const int* __restrict__ colS,
        const float* __restrict__ valS, const int* __restrict__ rowPtr,
        const float* __restrict__ src, float* __restrict__ dst) {
    const int lane = threadIdx.x & 63;
    const int row  = (int)((blockIdx.x * 256u + threadIdx.x) >> 6);
    const int beg = rowPtr[row], end = rowPtr[row + 1];
    float a0 = 0.f, a1 = 0.f;
    int i = beg;
    for (; i + 4 <= end; i += 4) {
        int c[4]; float v[4]; float g0[4], g1[4];
#pragma unroll
        for (int j = 0; j < 4; ++j) { c[j] = colS[i+j]; v[j] = valS[i+j]; }
#pragma unroll
        for (int j = 0; j < 4; ++j) {
            const float* sp = src + (size_t)c[j] * 128;
            g0[j] = sp[lane]; g1[j] = sp[64 + lane];
        }
#pragma unroll
        for (int j = 0; j < 4; ++j) { a0 += v[j]*g0[j]; a1 += v[j]*g1[j]; }
    }
    for (; i < end; ++i) {
        int c = colS[i]; float v = valS[i];
        a0 += v * src[(size_t)c*128 + lane];
        a1 += v * src[(size_t)c*128 + 64 + lane];
    }
    dst[(size_t)row*128 + lane]      = a0;
    dst[(size_t)row*128 + 64 + lane] = a1;
}

// t2 = adj@s2 fused with r2cat = relu(concat[s2-r1, t2-s2-r1])  (widths 128 -> 256)
__global__ __launch_bounds__(256) void spmm128f_kernel(const int* __restrict__ colS,
        const float* __restrict__ valS, const int* __restrict__ rowPtr,
        const float* __restrict__ s2, const float* __restrict__ r1,
        float* __restrict__ r2c) {
    const int lane = threadIdx.x & 63;
    const int row  = (int)((blockIdx.x * 256u + threadIdx.x) >> 6);
    const int beg = rowPtr[row], end = rowPtr[row + 1];
    float a0 = 0.f, a1 = 0.f;
    int i = beg;
    for (; i + 4 <= end; i += 4) {
        int c[4]; float v[4]; float g0[4], g1[4];
#pragma unroll
        for (int j = 0; j < 4; ++j) { c[j] = colS[i+j]; v[j] = valS[i+j]; }
#pragma unroll
        for (int j = 0; j < 4; ++j) {
            const float* sp = s2 + (size_t)c[j] * 128;
            g0[j] = sp[lane]; g1[j] = sp[64 + lane];
        }
#pragma unroll
        for (int j = 0; j < 4; ++j) { a0 += v[j]*g0[j]; a1 += v[j]*g1[j]; }
    }
    for (; i < end; ++i) {
        int c = colS[i]; float v = valS[i];
        a0 += v * s2[(size_t)c*128 + lane];
        a1 += v * s2[(size_t)c*128 + 64 + lane];
    }
    float s0v = s2[(size_t)row*128 + lane];
    float s1v = s2[(size_t)row*128 + 64 + lane];
    float r0v = r1[(size_t)row*128 + lane];
    float r1v = r1[(size_t)row*128 + 64 + lane];
    size_t ob = (size_t)row * 256 + lane;
    r2c[ob]        = fmaxf(s0v - r0v, 0.f);
    r2c[ob + 64]   = fmaxf(s1v - r1v, 0.f);
    r2c[ob + 128]  = fmaxf(a0 - s0v - r0v, 0.f);
    r2c[ob + 192]  = fmaxf(a1 - s1v - r1v, 0.f);
}

// ---------------- tiled GEMM: classify + softmax ----------------
// virtual concat [r0(64) | r1cat(128) | r2cat(256)] @ Wc[448,64], then row softmax.
// Row softmax: a row's 64 cols = 16 contiguous lanes x 4 regs -> shfl_xor(1,2,4,8).
__global__ __launch_bounds__(256) void classify_kernel(const float* __restrict__ r0,
        const float* __restrict__ r1, const float* __restrict__ r2,
        const float* __restrict__ wc, float* __restrict__ out) {
    __shared__ float lds_a[2][16 * APAD];
    __shared__ float lds_w[2][16 * 64];
    const int t    = threadIdx.x;
    const int row0 = blockIdx.x * 128;
    const int m0   = (t >> 4) * 8;
    const int n0   = (t & 15) * 4;
    const int srow = t >> 1;
    const int kk   = (t & 1) * 8;
    const int wrow = t >> 4;
    const int wcol = (t & 15) * 4;

    float acc[8][4];
#pragma unroll
    for (int i = 0; i < 8; ++i)
#pragma unroll
        for (int j = 0; j < 4; ++j) acc[i][j] = 0.f;

    // virtual-concat A pointer for k-tile kt (BK=16 never straddles 64/192 splits)
    auto aptr = [&](int kt) -> const float* {
        if (kt < 64)  return r0 + (size_t)(row0 + srow) * 64  + kt + kk;
        if (kt < 192) return r1 + (size_t)(row0 + srow) * 128 + (kt - 64) + kk;
        return               r2 + (size_t)(row0 + srow) * 256 + (kt - 192) + kk;
    };

    {
        const float* ap = aptr(0);
        float4 v0 = *(const float4*)(ap);
        float4 v1 = *(const float4*)(ap + 4);
        float4 pw = *(const float4*)(wc + (size_t)wrow * 64 + wcol);
        lds_a[0][(kk+0)*APAD + srow] = v0.x;
        lds_a[0][(kk+1)*APAD + srow] = v0.y;
        lds_a[0][(kk+2)*APAD + srow] = v0.z;
        lds_a[0][(kk+3)*APAD + srow] = v0.w;
        lds_a[0][(kk+4)*APAD + srow] = v1.x;
        lds_a[0][(kk+5)*APAD + srow] = v1.y;
        lds_a[0][(kk+6)*APAD + srow] = v1.z;
        lds_a[0][(kk+7)*APAD + srow] = v1.w;
        *(float4*)&lds_w[0][wrow * 64 + wcol] = pw;
    }
    __syncthreads();

    const int NSTEP = 28;  // 448/16
    for (int step = 0; step < NSTEP; ++step) {
        const int cur = step & 1;
        const bool more = (step + 1 < NSTEP);
        float4 v0, v1, pw;
        if (more) {
            int kt = (step + 1) * 16;
            const float* ap = aptr(kt);
            v0 = *(const float4*)(ap);
            v1 = *(const float4*)(ap + 4);
            pw = *(const float4*)(wc + (size_t)(kt + wrow) * 64 + wcol);
        }
#pragma unroll
        for (int k = 0; k < 16; ++k) {
            float4 a0 = *(const float4*)&lds_a[cur][k * APAD + m0];
            float4 a1 = *(const float4*)&lds_a[cur][k * APAD + m0 + 4];
            float4 wv = *(const float4*)&lds_w[cur][k * 64 + n0];
            float aa[8] = {a0.x,a0.y,a0.z,a0.w,a1.x,a1.y,a1.z,a1.w};
            float ww[4] = {wv.x,wv.y,wv.z,wv.w};
#pragma unroll
            for (int i = 0; i < 8; ++i)
#pragma unroll
                for (int j = 0; j < 4; ++j) acc[i][j] += aa[i] * ww[j];
        }
        if (more) {
            const int nb = cur ^ 1;
            lds_a[nb][(kk+0)*APAD + srow] = v0.x;
            lds_a[nb][(kk+1)*APAD + srow] = v0.y;
            lds_a[nb][(kk+2)*APAD + srow] = v0.z;
            lds_a[nb][(kk+3)*APAD + srow] = v0.w;
            lds_a[nb][(kk+4)*APAD + srow] = v1.x;
            lds_a[nb][(kk+5)*APAD + srow] = v1.y;
            lds_a[nb][(kk+6)*APAD + srow] = v1.z;
            lds_a[nb][(kk+7)*APAD + srow] = v1.w;
            *(float4*)&lds_w[nb][wrow * 64 + wcol] = pw;
        }
        __syncthreads();
    }

    // softmax over each row (16 lanes x 4 local cols) + store
#pragma unroll
    for (int i = 0; i < 8; ++i) {
        float m = fmaxf(fmaxf(acc[i][0], acc[i][1]), fmaxf(acc[i][2], acc[i][3]));
#pragma unroll
        for (int o = 1; o < 16; o <<= 1) m = fmaxf(m, __shfl_xor(m, o));
        float e0 = __expf(acc[i][0] - m);
        float e1 = __expf(acc[i][1] - m);
        float e2 = __expf(acc[i][2] - m);
        float e3 = __expf(acc[i][3] - m);
        float s = e0 + e1 + e2 + e3;
#pragma unroll
        for (int o = 1; o < 16; o <<= 1) s += __shfl_xor(s, o);
        float inv = 1.f / s;
        int rv = row0 + m0 + i;
        if (rv < N_NODES) {
            float4 o4 = {e0 * inv, e1 * inv, e2 * inv, e3 * inv};
            *(float4*)(out + (size_t)rv * 64 + n0) = o4;
        }
    }
}

extern "C" void kernel_launch(void* const* d_in, const int* in_sizes, int n_in,
                              void* d_out, int out_size, void* d_ws, size_t ws_size,
                              hipStream_t stream) {
    const float* x    = (const float*)d_in[0];
    const int*   erow = (const int*)d_in[1];
    const int*   ecol = (const int*)d_in[2];
    const float* eval = (const float*)d_in[3];
    const float* we   = (const float*)d_in[4];
    const float* wc   = (const float*)d_in[5];
    float* out = (float*)d_out;

    char* w = (char*)d_ws;
    size_t off = 0;
    auto take = [&](size_t bytes) {
        char* p = w + off;
        off += (bytes + 255) & ~(size_t)255;
        return p;
    };
    // padded to NPAD rows so 128-row tiles can read past 50000 safely
    float* r0     = (float*)take((size_t)NPAD * 64 * 4);
    float* sbuf   = (float*)take((size_t)NPAD * 128 * 4);  // s (w64) then s2 (w128)
    float* r1c    = (float*)take((size_t)NPAD * 128 * 4);
    float* r2c    = (float*)take((size_t)NPAD * 256 * 4);
    int*   cnt    = (int*)take((size_t)N_NODES * 4);
    int*   rowPtr = (int*)take((size_t)(N_NODES + 1) * 4);
    int*   fill   = (int*)take((size_t)N_NODES * 4);
    int*   bsum   = (int*)take((size_t)NB_SCAN * 4);
    int*   colS   = (int*)take((size_t)NEDGE * 4);
    float* valS   = (float*)take((size_t)NEDGE * 4);
    (void)ws_size; (void)in_sizes; (void)n_in; (void)out_size;

    hipMemsetAsync(cnt,  0, (size_t)N_NODES * 4, stream);
    hipMemsetAsync(fill, 0, (size_t)N_NODES * 4, stream);

    embed_kernel<<<NPAD / 128, 256, 0, stream>>>(x, we, r0);

    hist_kernel<<<3125, 256, 0, stream>>>(erow, cnt);
    scan_a<<<NB_SCAN, 256, 0, stream>>>(cnt, bsum);
    scan_b<<<1, 64, 0, stream>>>(bsum, rowPtr);
    scan_c<<<NB_SCAN, 256, 0, stream>>>(cnt, bsum, rowPtr);
    scatter_kernel<<<3125, 256, 0, stream>>>(erow, ecol, eval, rowPtr, fill, colS, valS);

    spmm64_kernel <<<12500, 256, 0, stream>>>(colS, valS, rowPtr, r0, sbuf);
    spmm64f_kernel<<<12500, 256, 0, stream>>>(colS, valS, rowPtr, sbuf, r0, r1c);
    spmm128_kernel<<<12500, 256, 0, stream>>>(colS, valS, rowPtr, r1c, sbuf);
    spmm128f_kernel<<<12500, 256, 0, stream>>>(colS, valS, rowPtr, sbuf, r1c, r2c);

    classify_kernel<<<NPAD / 128, 256, 0, stream>>>(r0, r1c, r2c, wc, out);
}

// Round 7
// 341.136 us; speedup vs baseline: 5.0669x; 1.1982x over previous
//
#include <hip/hip_runtime.h>

#define N_NODES 50000
#define NPAD 50048            // padded row count (multiple of 128)
#define FEAT 256
#define HID 64
#define NEDGE 800000
#define SCAN_CHUNK 2048
#define NB_SCAN 25  // ceil(50000/2048)
#define APAD 132              // A-tile LDS leading pad (k-major [16][APAD])

typedef unsigned short bf16_t;

__device__ __forceinline__ float bf2f(bf16_t b) {
    union { unsigned u; float f; } v; v.u = ((unsigned)b) << 16; return v.f;
}
__device__ __forceinline__ bf16_t f2bf(float f) {
    union { float f; unsigned u; } v; v.f = f;
    unsigned r = v.u + 0x7fff + ((v.u >> 16) & 1);   // RNE
    return (bf16_t)(r >> 16);
}
__device__ __forceinline__ void unpack2(unsigned u, float& lo, float& hi) {
    union { unsigned u; float f; } a, b;
    a.u = u << 16; b.u = u & 0xffff0000u;
    lo = a.f; hi = b.f;
}
__device__ __forceinline__ unsigned pack2(float lo, float hi) {
    return ((unsigned)f2bf(lo)) | (((unsigned)f2bf(hi)) << 16);
}

// ================= tiled GEMM common structure (from R6) =================
// BM=128, BN=64, BK=16, 256 threads. Thread (g=t>>4, q=t&15) owns 8x4 C tile.
// A staged k-major [16][APAD]; W staged [16][64]; double-buffered LDS.

// ---------------- embed: r0(bf16) = relu(x @ We) ----------------
__global__ __launch_bounds__(256) void embed_kernel(const float* __restrict__ x,
        const float* __restrict__ we, bf16_t* __restrict__ r0) {
    __shared__ float lds_a[2][16 * APAD];
    __shared__ float lds_w[2][16 * 64];
    const int t    = threadIdx.x;
    const int row0 = blockIdx.x * 128;
    const int m0   = (t >> 4) * 8;
    const int n0   = (t & 15) * 4;
    const int srow = t >> 1;          // 0..127
    const int kk   = (t & 1) * 8;     // 0 or 8
    const int wrow = t >> 4;          // 0..15
    const int wcol = (t & 15) * 4;

    int ar = row0 + srow;
    if (ar >= N_NODES) ar = N_NODES - 1;
    const float* axp = x + (size_t)ar * FEAT + kk;

    float acc[8][4];
#pragma unroll
    for (int i = 0; i < 8; ++i)
#pragma unroll
        for (int j = 0; j < 4; ++j) acc[i][j] = 0.f;

    {
        float4 v0 = *(const float4*)(axp + 0);
        float4 v1 = *(const float4*)(axp + 4);
        float4 pw = *(const float4*)(we + (size_t)wrow * 64 + wcol);
        lds_a[0][(kk+0)*APAD + srow] = v0.x;
        lds_a[0][(kk+1)*APAD + srow] = v0.y;
        lds_a[0][(kk+2)*APAD + srow] = v0.z;
        lds_a[0][(kk+3)*APAD + srow] = v0.w;
        lds_a[0][(kk+4)*APAD + srow] = v1.x;
        lds_a[0][(kk+5)*APAD + srow] = v1.y;
        lds_a[0][(kk+6)*APAD + srow] = v1.z;
        lds_a[0][(kk+7)*APAD + srow] = v1.w;
        *(float4*)&lds_w[0][wrow * 64 + wcol] = pw;
    }
    __syncthreads();

    const int NSTEP = FEAT / 16;  // 16
    for (int step = 0; step < NSTEP; ++step) {
        const int cur = step & 1;
        const bool more = (step + 1 < NSTEP);
        float4 v0, v1, pw;
        if (more) {
            int kt = (step + 1) * 16;
            v0 = *(const float4*)(axp + kt);
            v1 = *(const float4*)(axp + kt + 4);
            pw = *(const float4*)(we + (size_t)(kt + wrow) * 64 + wcol);
        }
#pragma unroll
        for (int k = 0; k < 16; ++k) {
            float4 a0 = *(const float4*)&lds_a[cur][k * APAD + m0];
            float4 a1 = *(const float4*)&lds_a[cur][k * APAD + m0 + 4];
            float4 wv = *(const float4*)&lds_w[cur][k * 64 + n0];
            float aa[8] = {a0.x,a0.y,a0.z,a0.w,a1.x,a1.y,a1.z,a1.w};
            float ww[4] = {wv.x,wv.y,wv.z,wv.w};
#pragma unroll
            for (int i = 0; i < 8; ++i)
#pragma unroll
                for (int j = 0; j < 4; ++j) acc[i][j] += aa[i] * ww[j];
        }
        if (more) {
            const int nb = cur ^ 1;
            lds_a[nb][(kk+0)*APAD + srow] = v0.x;
            lds_a[nb][(kk+1)*APAD + srow] = v0.y;
            lds_a[nb][(kk+2)*APAD + srow] = v0.z;
            lds_a[nb][(kk+3)*APAD + srow] = v0.w;
            lds_a[nb][(kk+4)*APAD + srow] = v1.x;
            lds_a[nb][(kk+5)*APAD + srow] = v1.y;
            lds_a[nb][(kk+6)*APAD + srow] = v1.z;
            lds_a[nb][(kk+7)*APAD + srow] = v1.w;
            *(float4*)&lds_w[nb][wrow * 64 + wcol] = pw;
        }
        __syncthreads();
    }

#pragma unroll
    for (int i = 0; i < 8; ++i) {
        int rv = row0 + m0 + i;
        if (rv < N_NODES) {
            unsigned lo = pack2(fmaxf(acc[i][0], 0.f), fmaxf(acc[i][1], 0.f));
            unsigned hi = pack2(fmaxf(acc[i][2], 0.f), fmaxf(acc[i][3], 0.f));
            uint2 u2; u2.x = lo; u2.y = hi;
            *(uint2*)(r0 + (size_t)rv * HID + n0) = u2;
        }
    }
}

// ---------------- CSR build ----------------
__global__ __launch_bounds__(256) void hist_kernel(const int* __restrict__ rows,
        int* __restrict__ cnt) {
    int e = blockIdx.x * 256 + threadIdx.x;
    if (e < NEDGE) atomicAdd(&cnt[rows[e]], 1);
}

__global__ __launch_bounds__(256) void scan_a(const int* __restrict__ cnt,
        int* __restrict__ bsum) {
    __shared__ int sd[256];
    const int t = threadIdx.x;
    const int base = blockIdx.x * SCAN_CHUNK + t * 8;
    int s = 0;
#pragma unroll
    for (int i = 0; i < 8; ++i) {
        int idx = base + i;
        s += (idx < N_NODES) ? cnt[idx] : 0;
    }
    sd[t] = s; __syncthreads();
    for (int off = 128; off > 0; off >>= 1) {
        if (t < off) sd[t] += sd[t + off];
        __syncthreads();
    }
    if (t == 0) bsum[blockIdx.x] = sd[0];
}

__global__ __launch_bounds__(64) void scan_b(int* __restrict__ bsum,
        int* __restrict__ rowPtr) {
    if (threadIdx.x == 0) {
        int run = 0;
        for (int b = 0; b < NB_SCAN; ++b) {
            int v = bsum[b];
            bsum[b] = run;
            run += v;
        }
        rowPtr[N_NODES] = run;
    }
}

__global__ __launch_bounds__(256) void scan_c(const int* __restrict__ cnt,
        const int* __restrict__ boff, int* __restrict__ rowPtr) {
    __shared__ int sd[256];
    const int t = threadIdx.x;
    const int base = blockIdx.x * SCAN_CHUNK + t * 8;
    int v[8];
    int s = 0;
#pragma unroll
    for (int i = 0; i < 8; ++i) {
        int idx = base + i;
        v[i] = (idx < N_NODES) ? cnt[idx] : 0;
        s += v[i];
    }
    sd[t] = s; __syncthreads();
    for (int off = 1; off < 256; off <<= 1) {
        int add = (t >= off) ? sd[t - off] : 0;
        __syncthreads();
        sd[t] += add;
        __syncthreads();
    }
    int run = boff[blockIdx.x] + (sd[t] - s);
#pragma unroll
    for (int i = 0; i < 8; ++i) {
        int idx = base + i;
        if (idx < N_NODES) rowPtr[idx] = run;
        run += v[i];
    }
}

__global__ __launch_bounds__(256) void scatter_kernel(const int* __restrict__ rows,
        const int* __restrict__ cols, const float* __restrict__ vals,
        const int* __restrict__ rowPtr, int* __restrict__ fill,
        int* __restrict__ colS, float* __restrict__ valS) {
    int e = blockIdx.x * 256 + threadIdx.x;
    if (e < NEDGE) {
        int r = rows[e];
        int p = rowPtr[r] + atomicAdd(&fill[r], 1);
        colS[p] = cols[e];
        valS[p] = vals[e];
    }
}

// ---------------- SpMM (CSR, one wave per row; bf16 storage, fp32 accum) ----------------
// width 64: lane = feature; gather = 2B/lane (wave 128B contiguous)
__global__ __launch_bounds__(256) void spmm64_kernel(const int* __restrict__ colS,
        const float* __restrict__ valS, const int* __restrict__ rowPtr,
        const bf16_t* __restrict__ src, bf16_t* __restrict__ dst) {
    const int lane = threadIdx.x & 63;
    const int row  = (int)((blockIdx.x * 256u + threadIdx.x) >> 6);
    const int beg = rowPtr[row], end = rowPtr[row + 1];
    float acc = 0.f;
    int i = beg;
    for (; i + 8 <= end; i += 8) {
        int   c[8]; float v[8]; float g[8];
#pragma unroll
        for (int j = 0; j < 8; ++j) { c[j] = colS[i+j]; v[j] = valS[i+j]; }
#pragma unroll
        for (int j = 0; j < 8; ++j) g[j] = bf2f(src[(size_t)c[j]*HID + lane]);
#pragma unroll
        for (int j = 0; j < 8; ++j) acc += v[j]*g[j];
    }
    for (; i < end; ++i)
        acc += valS[i] * bf2f(src[(size_t)colS[i]*HID + lane]);
    dst[(size_t)row*HID + lane] = f2bf(acc);
}

// t = adj@s fused with r1cat = relu(concat[s-r0, t-s-r0])
__global__ __launch_bounds__(256) void spmm64f_kernel(const int* __restrict__ colS,
        const float* __restrict__ valS, const int* __restrict__ rowPtr,
        const bf16_t* __restrict__ s, const bf16_t* __restrict__ r0,
        bf16_t* __restrict__ r1c) {
    const int lane = threadIdx.x & 63;
    const int row  = (int)((blockIdx.x * 256u + threadIdx.x) >> 6);
    const int beg = rowPtr[row], end = rowPtr[row + 1];
    float acc = 0.f;
    int i = beg;
    for (; i + 8 <= end; i += 8) {
        int   c[8]; float v[8]; float g[8];
#pragma unroll
        for (int j = 0; j < 8; ++j) { c[j] = colS[i+j]; v[j] = valS[i+j]; }
#pragma unroll
        for (int j = 0; j < 8; ++j) g[j] = bf2f(s[(size_t)c[j]*HID + lane]);
#pragma unroll
        for (int j = 0; j < 8; ++j) acc += v[j]*g[j];
    }
    for (; i < end; ++i)
        acc += valS[i] * bf2f(s[(size_t)colS[i]*HID + lane]);
    float sv = bf2f(s[(size_t)row*HID + lane]);
    float rv = bf2f(r0[(size_t)row*HID + lane]);
    r1c[(size_t)row*128 + lane]      = f2bf(fmaxf(sv - rv, 0.f));
    r1c[(size_t)row*128 + 64 + lane] = f2bf(fmaxf(acc - sv - rv, 0.f));
}

// width 128: lane handles elements {2*lane, 2*lane+1}; gather = packed uint (2xbf16)
__global__ __launch_bounds__(256) void spmm128_kernel(const int* __restrict__ colS,
        const float* __restrict__ valS, const int* __restrict__ rowPtr,
        const bf16_t* __restrict__ src, bf16_t* __restrict__ dst) {
    const int lane = threadIdx.x & 63;
    const int row  = (int)((blockIdx.x * 256u + threadIdx.x) >> 6);
    const int beg = rowPtr[row], end = rowPtr[row + 1];
    const unsigned* srcu = (const unsigned*)src;  // row stride 64 uints
    float a0 = 0.f, a1 = 0.f;
    int i = beg;
    for (; i + 4 <= end; i += 4) {
        int c[4]; float v[4]; unsigned u[4];
#pragma unroll
        for (int j = 0; j < 4; ++j) { c[j] = colS[i+j]; v[j] = valS[i+j]; }
#pragma unroll
        for (int j = 0; j < 4; ++j) u[j] = srcu[(size_t)c[j]*64 + lane];
#pragma unroll
        for (int j = 0; j < 4; ++j) {
            float lo, hi; unpack2(u[j], lo, hi);
            a0 += v[j]*lo; a1 += v[j]*hi;
        }
    }
    for (; i < end; ++i) {
        float lo, hi; unpack2(srcu[(size_t)colS[i]*64 + lane], lo, hi);
        a0 += valS[i]*lo; a1 += valS[i]*hi;
    }
    ((unsigned*)dst)[(size_t)row*64 + lane] = pack2(a0, a1);
}

// t2 = adj@s2 fused with r2cat = relu(concat[s2-r1, t2-s2-r1])
__global__ __launch_bounds__(256) void spmm128f_kernel(const int* __restrict__ colS,
        const float* __restrict__ valS, const int* __restrict__ rowPtr,
        const bf16_t* __restrict__ s2, const bf16_t* __restrict__ r1,
        bf16_t* __restrict__ r2c) {
    const int lane = threadIdx.x & 63;
    const int row  = (int)((blockIdx.x * 256u + threadIdx.x) >> 6);
    const int beg = rowPtr[row], end = rowPtr[row + 1];
    const unsigned* s2u = (const unsigned*)s2;
    const unsigned* r1u = (const unsigned*)r1;
    float a0 = 0.f, a1 = 0.f;
    int i = beg;
    for (; i + 4 <= end; i += 4) {
        int c[4]; float v[4]; unsigned u[4];
#pragma unroll
        for (int j = 0; j < 4; ++j) { c[j] = colS[i+j]; v[j] = valS[i+j]; }
#pragma unroll
        for (int j = 0; j < 4; ++j) u[j] = s2u[(size_t)c[j]*64 + lane];
#pragma unroll
        for (int j = 0; j < 4; ++j) {
            float lo, hi; unpack2(u[j], lo, hi);
            a0 += v[j]*lo; a1 += v[j]*hi;
        }
    }
    for (; i < end; ++i) {
        float lo, hi; unpack2(s2u[(size_t)colS[i]*64 + lane], lo, hi);
        a0 += valS[i]*lo; a1 += valS[i]*hi;
    }
    float s0v, s1v, r0v, r1v;
    unpack2(s2u[(size_t)row*64 + lane], s0v, s1v);
    unpack2(r1u[(size_t)row*64 + lane], r0v, r1v);
    unsigned* r2u = (unsigned*)r2c;  // row stride 128 uints
    r2u[(size_t)row*128 + lane]      = pack2(fmaxf(s0v - r0v, 0.f), fmaxf(s1v - r1v, 0.f));
    r2u[(size_t)row*128 + 64 + lane] = pack2(fmaxf(a0 - s0v - r0v, 0.f), fmaxf(a1 - s1v - r1v, 0.f));
}

// ---------------- tiled GEMM: classify + softmax ----------------
// virtual concat [r0(64) | r1cat(128) | r2cat(256)] (bf16) @ Wc[448,64] (fp32)
__global__ __launch_bounds__(256) void classify_kernel(const bf16_t* __restrict__ r0,
        const bf16_t* __restrict__ r1, const bf16_t* __restrict__ r2,
        const float* __restrict__ wc, float* __restrict__ out) {
    __shared__ float lds_a[2][16 * APAD];
    __shared__ float lds_w[2][16 * 64];
    const int t    = threadIdx.x;
    const int row0 = blockIdx.x * 128;
    const int m0   = (t >> 4) * 8;
    const int n0   = (t & 15) * 4;
    const int srow = t >> 1;
    const int kk   = (t & 1) * 8;
    const int wrow = t >> 4;
    const int wcol = (t & 15) * 4;

    float acc[8][4];
#pragma unroll
    for (int i = 0; i < 8; ++i)
#pragma unroll
        for (int j = 0; j < 4; ++j) acc[i][j] = 0.f;

    // virtual-concat A pointer for k-tile kt (BK=16 never straddles segment splits)
    auto aptr = [&](int kt) -> const bf16_t* {
        if (kt < 64)  return r0 + (size_t)(row0 + srow) * 64  + kt + kk;
        if (kt < 192) return r1 + (size_t)(row0 + srow) * 128 + (kt - 64) + kk;
        return               r2 + (size_t)(row0 + srow) * 256 + (kt - 192) + kk;
    };
    auto stage_a = [&](int buf, uint4 u) {
        float f0,f1,f2,f3,f4,f5,f6,f7;
        unpack2(u.x, f0, f1); unpack2(u.y, f2, f3);
        unpack2(u.z, f4, f5); unpack2(u.w, f6, f7);
        lds_a[buf][(kk+0)*APAD + srow] = f0;
        lds_a[buf][(kk+1)*APAD + srow] = f1;
        lds_a[buf][(kk+2)*APAD + srow] = f2;
        lds_a[buf][(kk+3)*APAD + srow] = f3;
        lds_a[buf][(kk+4)*APAD + srow] = f4;
        lds_a[buf][(kk+5)*APAD + srow] = f5;
        lds_a[buf][(kk+6)*APAD + srow] = f6;
        lds_a[buf][(kk+7)*APAD + srow] = f7;
    };

    {
        uint4 u = *(const uint4*)aptr(0);
        float4 pw = *(const float4*)(wc + (size_t)wrow * 64 + wcol);
        stage_a(0, u);
        *(float4*)&lds_w[0][wrow * 64 + wcol] = pw;
    }
    __syncthreads();

    const int NSTEP = 28;  // 448/16
    for (int step = 0; step < NSTEP; ++step) {
        const int cur = step & 1;
        const bool more = (step + 1 < NSTEP);
        uint4 ua; float4 pw;
        if (more) {
            int kt = (step + 1) * 16;
            ua = *(const uint4*)aptr(kt);
            pw = *(const float4*)(wc + (size_t)(kt + wrow) * 64 + wcol);
        }
#pragma unroll
        for (int k = 0; k < 16; ++k) {
            float4 a0 = *(const float4*)&lds_a[cur][k * APAD + m0];
            float4 a1 = *(const float4*)&lds_a[cur][k * APAD + m0 + 4];
            float4 wv = *(const float4*)&lds_w[cur][k * 64 + n0];
            float aa[8] = {a0.x,a0.y,a0.z,a0.w,a1.x,a1.y,a1.z,a1.w};
            float ww[4] = {wv.x,wv.y,wv.z,wv.w};
#pragma unroll
            for (int i = 0; i < 8; ++i)
#pragma unroll
                for (int j = 0; j < 4; ++j) acc[i][j] += aa[i] * ww[j];
        }
        if (more) {
            stage_a(cur ^ 1, ua);
            *(float4*)&lds_w[cur ^ 1][wrow * 64 + wcol] = pw;
        }
        __syncthreads();
    }

    // softmax over each row (16 lanes x 4 local cols) + store
#pragma unroll
    for (int i = 0; i < 8; ++i) {
        float m = fmaxf(fmaxf(acc[i][0], acc[i][1]), fmaxf(acc[i][2], acc[i][3]));
#pragma unroll
        for (int o = 1; o < 16; o <<= 1) m = fmaxf(m, __shfl_xor(m, o));
        float e0 = __expf(acc[i][0] - m);
        float e1 = __expf(acc[i][1] - m);
        float e2 = __expf(acc[i][2] - m);
        float e3 = __expf(acc[i][3] - m);
        float s = e0 + e1 + e2 + e3;
#pragma unroll
        for (int o = 1; o < 16; o <<= 1) s += __shfl_xor(s, o);
        float inv = 1.f / s;
        int rv = row0 + m0 + i;
        if (rv < N_NODES) {
            float4 o4 = {e0 * inv, e1 * inv, e2 * inv, e3 * inv};
            *(float4*)(out + (size_t)rv * 64 + n0) = o4;
        }
    }
}

extern "C" void kernel_launch(void* const* d_in, const int* in_sizes, int n_in,
                              void* d_out, int out_size, void* d_ws, size_t ws_size,
                              hipStream_t stream) {
    const float* x    = (const float*)d_in[0];
    const int*   erow = (const int*)d_in[1];
    const int*   ecol = (const int*)d_in[2];
    const float* eval = (const float*)d_in[3];
    const float* we   = (const float*)d_in[4];
    const float* wc   = (const float*)d_in[5];
    float* out = (float*)d_out;

    char* w = (char*)d_ws;
    size_t off = 0;
    auto take = [&](size_t bytes) {
        char* p = w + off;
        off += (bytes + 255) & ~(size_t)255;
        return p;
    };
    // bf16 activation buffers (padded to NPAD rows)
    bf16_t* r0     = (bf16_t*)take((size_t)NPAD * 64 * 2);
    bf16_t* sbuf   = (bf16_t*)take((size_t)NPAD * 128 * 2);  // s (w64) then s2 (w128)
    bf16_t* r1c    = (bf16_t*)take((size_t)NPAD * 128 * 2);
    bf16_t* r2c    = (bf16_t*)take((size_t)NPAD * 256 * 2);
    int*   cnt    = (int*)take((size_t)N_NODES * 4);
    int*   rowPtr = (int*)take((size_t)(N_NODES + 1) * 4);
    int*   fill   = (int*)take((size_t)N_NODES * 4);
    int*   bsum   = (int*)take((size_t)NB_SCAN * 4);
    int*   colS   = (int*)take((size_t)NEDGE * 4);
    float* valS   = (float*)take((size_t)NEDGE * 4);
    (void)ws_size; (void)in_sizes; (void)n_in; (void)out_size;

    hipMemsetAsync(cnt,  0, (size_t)N_NODES * 4, stream);
    hipMemsetAsync(fill, 0, (size_t)N_NODES * 4, stream);

    embed_kernel<<<NPAD / 128, 256, 0, stream>>>(x, we, r0);

    hist_kernel<<<3125, 256, 0, stream>>>(erow, cnt);
    scan_a<<<NB_SCAN, 256, 0, stream>>>(cnt, bsum);
    scan_b<<<1, 64, 0, stream>>>(bsum, rowPtr);
    scan_c<<<NB_SCAN, 256, 0, stream>>>(cnt, bsum, rowPtr);
    scatter_kernel<<<3125, 256, 0, stream>>>(erow, ecol, eval, rowPtr, fill, colS, valS);

    spmm64_kernel <<<12500, 256, 0, stream>>>(colS, valS, rowPtr, r0, sbuf);
    spmm64f_kernel<<<12500, 256, 0, stream>>>(colS, valS, rowPtr, sbuf, r0, r1c);
    spmm128_kernel<<<12500, 256, 0, stream>>>(colS, valS, rowPtr, r1c, sbuf);
    spmm128f_kernel<<<12500, 256, 0, stream>>>(colS, valS, rowPtr, sbuf, r1c, r2c);

    classify_kernel<<<NPAD / 128, 256, 0, stream>>>(r0, r1c, r2c, wc, out);
}

// Round 8
// 277.192 us; speedup vs baseline: 6.2357x; 1.2307x over previous
//
#include <hip/hip_runtime.h>

#define N_NODES 50000
#define NPAD 50048            // padded row count (multiple of 128)
#define FEAT 256
#define HID 64
#define NEDGE 800000
#define SCAN_CHUNK 2048
#define NB_SCAN 25  // ceil(50000/2048)

typedef unsigned short bf16_t;
typedef __attribute__((ext_vector_type(8))) short bf16x8;   // 8 bf16 = 4 VGPR
typedef __attribute__((ext_vector_type(4))) float f32x4;

#define MFMA_BF16 __builtin_amdgcn_mfma_f32_16x16x32_bf16

__device__ __forceinline__ float bf2f(bf16_t b) {
    union { unsigned u; float f; } v; v.u = ((unsigned)b) << 16; return v.f;
}
__device__ __forceinline__ bf16_t f2bf(float f) {
    union { float f; unsigned u; } v; v.f = f;
    unsigned r = v.u + 0x7fff + ((v.u >> 16) & 1);   // RNE
    return (bf16_t)(r >> 16);
}
__device__ __forceinline__ void unpack2(unsigned u, float& lo, float& hi) {
    union { unsigned u; float f; } a, b;
    a.u = u << 16; b.u = u & 0xffff0000u;
    lo = a.f; hi = b.f;
}
__device__ __forceinline__ unsigned pack2(float lo, float hi) {
    return ((unsigned)f2bf(lo)) | (((unsigned)f2bf(hi)) << 16);
}

// ---------------- weight pack: fragment-order bf16 ----------------
// dst entry idx=(ks*4+nt)*64+lane holds 8 bf16: w[ks*32+(lane>>4)*8+j][nt*16+(lane&15)]
// (same intra-lane k-order as the A-fragment loads -> consistent contraction)
__global__ __launch_bounds__(256) void pack_w_kernel(const float* __restrict__ wsrc,
        bf16_t* __restrict__ wdst, int nkstep) {
    int idx = blockIdx.x * 256 + threadIdx.x;
    if (idx >= nkstep * 256) return;
    int lane = idx & 63, nt = (idx >> 6) & 3, ks = idx >> 8;
    int kb  = ks * 32 + ((lane >> 4) * 8);
    int col = nt * 16 + (lane & 15);
    unsigned p[4];
#pragma unroll
    for (int j = 0; j < 4; ++j)
        p[j] = pack2(wsrc[(size_t)(kb + 2*j) * 64 + col],
                     wsrc[(size_t)(kb + 2*j + 1) * 64 + col]);
    uint4 u; u.x = p[0]; u.y = p[1]; u.z = p[2]; u.w = p[3];
    *(uint4*)(wdst + (size_t)idx * 8) = u;
}

// ---------------- embed (MFMA): r0(bf16) = relu(x @ We) ----------------
// 256 thr = 4 waves; wave w: rows blk*128 + w*32 .. +31 (2 row-tiles x 4 col-tiles)
__global__ __launch_bounds__(256) void embed_mfma(const float* __restrict__ x,
        const bf16_t* __restrict__ wep, bf16_t* __restrict__ r0) {
    const int t = threadIdx.x;
    const int l = t & 63, w = t >> 6;
    const int lm = l & 15, lg = l >> 4;
    const int base = blockIdx.x * 128 + w * 32;

    int m0 = base + lm, m1 = base + 16 + lm;
    if (m0 >= N_NODES) m0 = N_NODES - 1;
    if (m1 >= N_NODES) m1 = N_NODES - 1;
    const float* xp0 = x + (size_t)m0 * FEAT + lg * 8;
    const float* xp1 = x + (size_t)m1 * FEAT + lg * 8;

    f32x4 acc[2][4];
#pragma unroll
    for (int i = 0; i < 2; ++i)
#pragma unroll
        for (int j = 0; j < 4; ++j) acc[i][j] = (f32x4){0.f, 0.f, 0.f, 0.f};

    auto aload = [&](const float* p) {
        float4 u0 = *(const float4*)(p);
        float4 u1 = *(const float4*)(p + 4);
        bf16x8 r;
        r[0] = (short)f2bf(u0.x); r[1] = (short)f2bf(u0.y);
        r[2] = (short)f2bf(u0.z); r[3] = (short)f2bf(u0.w);
        r[4] = (short)f2bf(u1.x); r[5] = (short)f2bf(u1.y);
        r[6] = (short)f2bf(u1.z); r[7] = (short)f2bf(u1.w);
        return r;
    };
    auto wb = [&](int ks, int nt) {
        return *(const bf16x8*)(wep + ((size_t)(ks * 4 + nt) * 64 + l) * 8);
    };

    const int NK = FEAT / 32;  // 8
    bf16x8 a0 = aload(xp0), a1 = aload(xp1);
    bf16x8 b0 = wb(0,0), b1 = wb(0,1), b2 = wb(0,2), b3 = wb(0,3);
    for (int ks = 0; ks < NK; ++ks) {
        bf16x8 na0, na1, nb0, nb1, nb2, nb3;
        const bool more = (ks + 1 < NK);
        if (more) {
            int kt = (ks + 1) * 32;
            na0 = aload(xp0 + kt); na1 = aload(xp1 + kt);
            nb0 = wb(ks+1,0); nb1 = wb(ks+1,1); nb2 = wb(ks+1,2); nb3 = wb(ks+1,3);
        }
        acc[0][0] = MFMA_BF16(a0, b0, acc[0][0], 0, 0, 0);
        acc[1][0] = MFMA_BF16(a1, b0, acc[1][0], 0, 0, 0);
        acc[0][1] = MFMA_BF16(a0, b1, acc[0][1], 0, 0, 0);
        acc[1][1] = MFMA_BF16(a1, b1, acc[1][1], 0, 0, 0);
        acc[0][2] = MFMA_BF16(a0, b2, acc[0][2], 0, 0, 0);
        acc[1][2] = MFMA_BF16(a1, b2, acc[1][2], 0, 0, 0);
        acc[0][3] = MFMA_BF16(a0, b3, acc[0][3], 0, 0, 0);
        acc[1][3] = MFMA_BF16(a1, b3, acc[1][3], 0, 0, 0);
        if (more) { a0 = na0; a1 = na1; b0 = nb0; b1 = nb1; b2 = nb2; b3 = nb3; }
    }

    // C layout: row=(lg)*4+reg (within 16-row tile), col=nt*16+lm
#pragma unroll
    for (int rt = 0; rt < 2; ++rt)
#pragma unroll
        for (int r = 0; r < 4; ++r) {
            int R = base + rt * 16 + lg * 4 + r;
            if (R < N_NODES) {
                bf16_t* o = r0 + (size_t)R * HID + lm;
                o[0]  = f2bf(fmaxf(acc[rt][0][r], 0.f));
                o[16] = f2bf(fmaxf(acc[rt][1][r], 0.f));
                o[32] = f2bf(fmaxf(acc[rt][2][r], 0.f));
                o[48] = f2bf(fmaxf(acc[rt][3][r], 0.f));
            }
        }
}

// ---------------- CSR build ----------------
__global__ __launch_bounds__(256) void hist_kernel(const int* __restrict__ rows,
        int* __restrict__ cnt) {
    int e = blockIdx.x * 256 + threadIdx.x;
    if (e < NEDGE) atomicAdd(&cnt[rows[e]], 1);
}

__global__ __launch_bounds__(256) void scan_a(const int* __restrict__ cnt,
        int* __restrict__ bsum) {
    __shared__ int sd[256];
    const int t = threadIdx.x;
    const int base = blockIdx.x * SCAN_CHUNK + t * 8;
    int s = 0;
#pragma unroll
    for (int i = 0; i < 8; ++i) {
        int idx = base + i;
        s += (idx < N_NODES) ? cnt[idx] : 0;
    }
    sd[t] = s; __syncthreads();
    for (int off = 128; off > 0; off >>= 1) {
        if (t < off) sd[t] += sd[t + off];
        __syncthreads();
    }
    if (t == 0) bsum[blockIdx.x] = sd[0];
}

__global__ __launch_bounds__(64) void scan_b(int* __restrict__ bsum,
        int* __restrict__ rowPtr) {
    if (threadIdx.x == 0) {
        int run = 0;
        for (int b = 0; b < NB_SCAN; ++b) {
            int v = bsum[b];
            bsum[b] = run;
            run += v;
        }
        rowPtr[N_NODES] = run;
    }
}

__global__ __launch_bounds__(256) void scan_c(const int* __restrict__ cnt,
        const int* __restrict__ boff, int* __restrict__ rowPtr) {
    __shared__ int sd[256];
    const int t = threadIdx.x;
    const int base = blockIdx.x * SCAN_CHUNK + t * 8;
    int v[8];
    int s = 0;
#pragma unroll
    for (int i = 0; i < 8; ++i) {
        int idx = base + i;
        v[i] = (idx < N_NODES) ? cnt[idx] : 0;
        s += v[i];
    }
    sd[t] = s; __syncthreads();
    for (int off = 1; off < 256; off <<= 1) {
        int add = (t >= off) ? sd[t - off] : 0;
        __syncthreads();
        sd[t] += add;
        __syncthreads();
    }
    int run = boff[blockIdx.x] + (sd[t] - s);
#pragma unroll
    for (int i = 0; i < 8; ++i) {
        int idx = base + i;
        if (idx < N_NODES) rowPtr[idx] = run;
        run += v[i];
    }
}

// single uint2 scatter per edge (halves randomly-touched cache lines vs 2 streams)
__global__ __launch_bounds__(256) void scatter_kernel(const int* __restrict__ rows,
        const int* __restrict__ cols, const float* __restrict__ vals,
        const int* __restrict__ rowPtr, int* __restrict__ fill,
        uint2* __restrict__ colval) {
    int e = blockIdx.x * 256 + threadIdx.x;
    if (e < NEDGE) {
        int r = rows[e];
        int p = rowPtr[r] + atomicAdd(&fill[r], 1);
        uint2 cv; cv.x = (unsigned)cols[e]; cv.y = __float_as_uint(vals[e]);
        colval[p] = cv;
    }
}

// ---------------- SpMM (CSR, one wave per row; bf16 storage, fp32 accum) ----------------
__global__ __launch_bounds__(256) void spmm64_kernel(const uint2* __restrict__ colval,
        const int* __restrict__ rowPtr,
        const bf16_t* __restrict__ src, bf16_t* __restrict__ dst) {
    const int lane = threadIdx.x & 63;
    const int row  = (int)((blockIdx.x * 256u + threadIdx.x) >> 6);
    const int beg = rowPtr[row], end = rowPtr[row + 1];
    float acc = 0.f;
    int i = beg;
    for (; i + 8 <= end; i += 8) {
        uint2 cv[8]; float g[8];
#pragma unroll
        for (int j = 0; j < 8; ++j) cv[j] = colval[i+j];
#pragma unroll
        for (int j = 0; j < 8; ++j) g[j] = bf2f(src[(size_t)cv[j].x*HID + lane]);
#pragma unroll
        for (int j = 0; j < 8; ++j) acc += __uint_as_float(cv[j].y)*g[j];
    }
    for (; i < end; ++i) {
        uint2 cv = colval[i];
        acc += __uint_as_float(cv.y) * bf2f(src[(size_t)cv.x*HID + lane]);
    }
    dst[(size_t)row*HID + lane] = f2bf(acc);
}

// t = adj@s fused with r1cat = relu(concat[s-r0, t-s-r0])
__global__ __launch_bounds__(256) void spmm64f_kernel(const uint2* __restrict__ colval,
        const int* __restrict__ rowPtr,
        const bf16_t* __restrict__ s, const bf16_t* __restrict__ r0,
        bf16_t* __restrict__ r1c) {
    const int lane = threadIdx.x & 63;
    const int row  = (int)((blockIdx.x * 256u + threadIdx.x) >> 6);
    const int beg = rowPtr[row], end = rowPtr[row + 1];
    float acc = 0.f;
    int i = beg;
    for (; i + 8 <= end; i += 8) {
        uint2 cv[8]; float g[8];
#pragma unroll
        for (int j = 0; j < 8; ++j) cv[j] = colval[i+j];
#pragma unroll
        for (int j = 0; j < 8; ++j) g[j] = bf2f(s[(size_t)cv[j].x*HID + lane]);
#pragma unroll
        for (int j = 0; j < 8; ++j) acc += __uint_as_float(cv[j].y)*g[j];
    }
    for (; i < end; ++i) {
        uint2 cv = colval[i];
        acc += __uint_as_float(cv.y) * bf2f(s[(size_t)cv.x*HID + lane]);
    }
    float sv = bf2f(s[(size_t)row*HID + lane]);
    float rv = bf2f(r0[(size_t)row*HID + lane]);
    r1c[(size_t)row*128 + lane]      = f2bf(fmaxf(sv - rv, 0.f));
    r1c[(size_t)row*128 + 64 + lane] = f2bf(fmaxf(acc - sv - rv, 0.f));
}

__global__ __launch_bounds__(256) void spmm128_kernel(const uint2* __restrict__ colval,
        const int* __restrict__ rowPtr,
        const bf16_t* __restrict__ src, bf16_t* __restrict__ dst) {
    const int lane = threadIdx.x & 63;
    const int row  = (int)((blockIdx.x * 256u + threadIdx.x) >> 6);
    const int beg = rowPtr[row], end = rowPtr[row + 1];
    const unsigned* srcu = (const unsigned*)src;  // row stride 64 uints
    float a0 = 0.f, a1 = 0.f;
    int i = beg;
    for (; i + 4 <= end; i += 4) {
        uint2 cv[4]; unsigned u[4];
#pragma unroll
        for (int j = 0; j < 4; ++j) cv[j] = colval[i+j];
#pragma unroll
        for (int j = 0; j < 4; ++j) u[j] = srcu[(size_t)cv[j].x*64 + lane];
#pragma unroll
        for (int j = 0; j < 4; ++j) {
            float lo, hi; unpack2(u[j], lo, hi);
            float v = __uint_as_float(cv[j].y);
            a0 += v*lo; a1 += v*hi;
        }
    }
    for (; i < end; ++i) {
        uint2 cv = colval[i];
        float lo, hi; unpack2(srcu[(size_t)cv.x*64 + lane], lo, hi);
        float v = __uint_as_float(cv.y);
        a0 += v*lo; a1 += v*hi;
    }
    ((unsigned*)dst)[(size_t)row*64 + lane] = pack2(a0, a1);
}

__global__ __launch_bounds__(256) void spmm128f_kernel(const uint2* __restrict__ colval,
        const int* __restrict__ rowPtr,
        const bf16_t* __restrict__ s2, const bf16_t* __restrict__ r1,
        bf16_t* __restrict__ r2c) {
    const int lane = threadIdx.x & 63;
    const int row  = (int)((blockIdx.x * 256u + threadIdx.x) >> 6);
    const int beg = rowPtr[row], end = rowPtr[row + 1];
    const unsigned* s2u = (const unsigned*)s2;
    const unsigned* r1u = (const unsigned*)r1;
    float a0 = 0.f, a1 = 0.f;
    int i = beg;
    for (; i + 4 <= end; i += 4) {
        uint2 cv[4]; unsigned u[4];
#pragma unroll
        for (int j = 0; j < 4; ++j) cv[j] = colval[i+j];
#pragma unroll
        for (int j = 0; j < 4; ++j) u[j] = s2u[(size_t)cv[j].x*64 + lane];
#pragma unroll
        for (int j = 0; j < 4; ++j) {
            float lo, hi; unpack2(u[j], lo, hi);
            float v = __uint_as_float(cv[j].y);
            a0 += v*lo; a1 += v*hi;
        }
    }
    for (; i < end; ++i) {
        uint2 cv = colval[i];
        float lo, hi; unpack2(s2u[(size_t)cv.x*64 + lane], lo, hi);
        float v = __uint_as_float(cv.y);
        a0 += v*lo; a1 += v*hi;
    }
    float s0v, s1v, r0v, r1v;
    unpack2(s2u[(size_t)row*64 + lane], s0v, s1v);
    unpack2(r1u[(size_t)row*64 + lane], r0v, r1v);
    unsigned* r2u = (unsigned*)r2c;  // row stride 128 uints
    r2u[(size_t)row*128 + lane]      = pack2(fmaxf(s0v - r0v, 0.f), fmaxf(s1v - r1v, 0.f));
    r2u[(size_t)row*128 + 64 + lane] = pack2(fmaxf(a0 - s0v - r0v, 0.f), fmaxf(a1 - s1v - r1v, 0.f));
}

// ---------------- classify (MFMA) + softmax ----------------
// virtual concat [r0(64)|r1c(128)|r2c(256)] bf16 @ packed Wc[448,64] bf16, K-tiles of 32
__global__ __launch_bounds__(256) void classify_mfma(const bf16_t* __restrict__ r0,
        const bf16_t* __restrict__ r1, const bf16_t* __restrict__ r2,
        const bf16_t* __restrict__ wcp, float* __restrict__ out) {
    const int t = threadIdx.x;
    const int l = t & 63, w = t >> 6;
    const int lm = l & 15, lg = l >> 4;
    const int base = blockIdx.x * 128 + w * 32;

    const int m0 = base + lm, m1 = base + 16 + lm;   // padded buffers: reads safe
    const bf16_t* p0_r0 = r0 + (size_t)m0 * 64  + lg * 8;
    const bf16_t* p0_r1 = r1 + (size_t)m0 * 128 + lg * 8;
    const bf16_t* p0_r2 = r2 + (size_t)m0 * 256 + lg * 8;
    const bf16_t* p1_r0 = r0 + (size_t)m1 * 64  + lg * 8;
    const bf16_t* p1_r1 = r1 + (size_t)m1 * 128 + lg * 8;
    const bf16_t* p1_r2 = r2 + (size_t)m1 * 256 + lg * 8;

    f32x4 acc[2][4];
#pragma unroll
    for (int i = 0; i < 2; ++i)
#pragma unroll
        for (int j = 0; j < 4; ++j) acc[i][j] = (f32x4){0.f, 0.f, 0.f, 0.f};

    auto aload = [&](const bf16_t* pr0, const bf16_t* pr1, const bf16_t* pr2, int kt) {
        const bf16_t* p = (kt < 64) ? (pr0 + kt) : (kt < 192) ? (pr1 + kt - 64) : (pr2 + kt - 192);
        return *(const bf16x8*)p;
    };
    auto wb = [&](int ks, int nt) {
        return *(const bf16x8*)(wcp + ((size_t)(ks * 4 + nt) * 64 + l) * 8);
    };

    const int NK = 14;  // 448/32
    bf16x8 a0 = aload(p0_r0, p0_r1, p0_r2, 0);
    bf16x8 a1 = aload(p1_r0, p1_r1, p1_r2, 0);
    bf16x8 b0 = wb(0,0), b1 = wb(0,1), b2 = wb(0,2), b3 = wb(0,3);
    for (int ks = 0; ks < NK; ++ks) {
        bf16x8 na0, na1, nb0, nb1, nb2, nb3;
        const bool more = (ks + 1 < NK);
        if (more) {
            int kt = (ks + 1) * 32;
            na0 = aload(p0_r0, p0_r1, p0_r2, kt);
            na1 = aload(p1_r0, p1_r1, p1_r2, kt);
            nb0 = wb(ks+1,0); nb1 = wb(ks+1,1); nb2 = wb(ks+1,2); nb3 = wb(ks+1,3);
        }
        acc[0][0] = MFMA_BF16(a0, b0, acc[0][0], 0, 0, 0);
        acc[1][0] = MFMA_BF16(a1, b0, acc[1][0], 0, 0, 0);
        acc[0][1] = MFMA_BF16(a0, b1, acc[0][1], 0, 0, 0);
        acc[1][1] = MFMA_BF16(a1, b1, acc[1][1], 0, 0, 0);
        acc[0][2] = MFMA_BF16(a0, b2, acc[0][2], 0, 0, 0);
        acc[1][2] = MFMA_BF16(a1, b2, acc[1][2], 0, 0, 0);
        acc[0][3] = MFMA_BF16(a0, b3, acc[0][3], 0, 0, 0);
        acc[1][3] = MFMA_BF16(a1, b3, acc[1][3], 0, 0, 0);
        if (more) { a0 = na0; a1 = na1; b0 = nb0; b1 = nb1; b2 = nb2; b3 = nb3; }
    }

    // softmax per row: row R's 64 cols live in 16 lanes (same lg group) x 4 nt-slots
#pragma unroll
    for (int rt = 0; rt < 2; ++rt)
#pragma unroll
        for (int r = 0; r < 4; ++r) {
            float v0 = acc[rt][0][r], v1 = acc[rt][1][r];
            float v2 = acc[rt][2][r], v3 = acc[rt][3][r];
            float m = fmaxf(fmaxf(v0, v1), fmaxf(v2, v3));
#pragma unroll
            for (int o = 1; o < 16; o <<= 1) m = fmaxf(m, __shfl_xor(m, o));
            float e0 = __expf(v0 - m), e1 = __expf(v1 - m);
            float e2 = __expf(v2 - m), e3 = __expf(v3 - m);
            float s = e0 + e1 + e2 + e3;
#pragma unroll
            for (int o = 1; o < 16; o <<= 1) s += __shfl_xor(s, o);
            float inv = 1.f / s;
            int R = base + rt * 16 + lg * 4 + r;
            if (R < N_NODES) {
                float* o = out + (size_t)R * 64 + lm;
                o[0]  = e0 * inv;
                o[16] = e1 * inv;
                o[32] = e2 * inv;
                o[48] = e3 * inv;
            }
        }
}

extern "C" void kernel_launch(void* const* d_in, const int* in_sizes, int n_in,
                              void* d_out, int out_size, void* d_ws, size_t ws_size,
                              hipStream_t stream) {
    const float* x    = (const float*)d_in[0];
    const int*   erow = (const int*)d_in[1];
    const int*   ecol = (const int*)d_in[2];
    const float* eval = (const float*)d_in[3];
    const float* we   = (const float*)d_in[4];
    const float* wc   = (const float*)d_in[5];
    float* out = (float*)d_out;

    char* wsp = (char*)d_ws;
    size_t off = 0;
    auto take = [&](size_t bytes) {
        char* p = wsp + off;
        off += (bytes + 255) & ~(size_t)255;
        return p;
    };
    bf16_t* r0     = (bf16_t*)take((size_t)NPAD * 64 * 2);
    bf16_t* sbuf   = (bf16_t*)take((size_t)NPAD * 128 * 2);  // s (w64) then s2 (w128)
    bf16_t* r1c    = (bf16_t*)take((size_t)NPAD * 128 * 2);
    bf16_t* r2c    = (bf16_t*)take((size_t)NPAD * 256 * 2);
    int*    cnt    = (int*)take((size_t)N_NODES * 4);
    int*    rowPtr = (int*)take((size_t)(N_NODES + 1) * 4);
    int*    fill   = (int*)take((size_t)N_NODES * 4);
    int*    bsum   = (int*)take((size_t)NB_SCAN * 4);
    uint2*  colval = (uint2*)take((size_t)NEDGE * 8);
    bf16_t* wep    = (bf16_t*)take((size_t)8  * 256 * 8 * 2);   // 8 ksteps packed We
    bf16_t* wcp    = (bf16_t*)take((size_t)14 * 256 * 8 * 2);   // 14 ksteps packed Wc
    (void)ws_size; (void)in_sizes; (void)n_in; (void)out_size;

    hipMemsetAsync(cnt,  0, (size_t)N_NODES * 4, stream);
    hipMemsetAsync(fill, 0, (size_t)N_NODES * 4, stream);

    pack_w_kernel<<<8,  256, 0, stream>>>(we, wep, 8);
    pack_w_kernel<<<14, 256, 0, stream>>>(wc, wcp, 14);

    embed_mfma<<<NPAD / 128, 256, 0, stream>>>(x, wep, r0);

    hist_kernel<<<3125, 256, 0, stream>>>(erow, cnt);
    scan_a<<<NB_SCAN, 256, 0, stream>>>(cnt, bsum);
    scan_b<<<1, 64, 0, stream>>>(bsum, rowPtr);
    scan_c<<<NB_SCAN, 256, 0, stream>>>(cnt, bsum, rowPtr);
    scatter_kernel<<<3125, 256, 0, stream>>>(erow, ecol, eval, rowPtr, fill, colval);

    spmm64_kernel <<<12500, 256, 0, stream>>>(colval, rowPtr, r0, sbuf);
    spmm64f_kernel<<<12500, 256, 0, stream>>>(colval, rowPtr, sbuf, r0, r1c);
    spmm128_kernel<<<12500, 256, 0, stream>>>(colval, rowPtr, r1c, sbuf);
    spmm128f_kernel<<<12500, 256, 0, stream>>>(colval, rowPtr, sbuf, r1c, r2c);

    classify_mfma<<<NPAD / 128, 256, 0, stream>>>(r0, r1c, r2c, wcp, out);
}